// Round 1
// baseline (724.576 us; speedup 1.0000x reference)
//
#include <hip/hip_runtime.h>

#define N 512
#define LOGN 9
#define NF 257        // n_freq = N/2 + 1
#define NB 128        // batch
#define PI_F 3.14159265358979323846f

__device__ __forceinline__ int bitrev9(int x) {
    return (int)(__brev((unsigned)x) >> 23);
}

// ---------------- zero accumulators ----------------
__global__ void zero_kernel(float* __restrict__ acc, float* __restrict__ bins) {
    int i = blockIdx.x * blockDim.x + threadIdx.x;
    if (i < N * N) acc[i] = 0.0f;
    if (i < 2 * (NF + 1)) bins[i] = 0.0f;
}

// ---------------- per-image mean ----------------
__global__ __launch_bounds__(256) void mean_kernel(const float* __restrict__ x,
                                                   float* __restrict__ mean) {
    int b = blockIdx.x;
    const float4* p = (const float4*)(x + (size_t)b * N * N);
    float s = 0.0f;
    for (int i = threadIdx.x; i < N * N / 4; i += 256) {
        float4 v = p[i];
        s += (v.x + v.y) + (v.z + v.w);
    }
    __shared__ float red[256];
    red[threadIdx.x] = s;
    __syncthreads();
    for (int off = 128; off > 0; off >>= 1) {
        if (threadIdx.x < off) red[threadIdx.x] += red[threadIdx.x + off];
        __syncthreads();
    }
    if (threadIdx.x == 0) mean[b] = red[0] * (1.0f / (float)(N * N));
}

// ---------------- row FFT (with mean-subtract + Hann) ----------------
// block = 256 threads = 4 waves; each wave does one row's 512-pt FFT.
__global__ __launch_bounds__(256) void rowfft_kernel(const float* __restrict__ x,
                                                     const float* __restrict__ mean,
                                                     float2* __restrict__ inter,
                                                     int bstart) {
    __shared__ float re[4][N];
    __shared__ float im[4][N];
    __shared__ float2 tw[N / 2];
    int t = threadIdx.x;
    // twiddle table: tw[i] = exp(-2*pi*i*I/N)
    if (t < N / 2) {
        float sv, cv;
        sincosf(-PI_F * (float)t * (1.0f / (float)(N / 2)), &sv, &cv);
        tw[t] = make_float2(cv, sv);
    }
    int ri   = t >> 6;          // wave id = local row
    int lane = t & 63;
    int gr = blockIdx.x * 4 + ri;        // row within chunk
    int bi = gr >> LOGN;                 // image within chunk
    int r  = gr & (N - 1);               // row index
    int b  = bstart + bi;                // global image
    float mn = mean[b];
    const float* xrow = x + ((size_t)b * N + r) * N;

    const float step = (float)N / (float)(N - 1);     // linspace(-256,256,512) step
    float lr = -0.5f * (float)N + (float)r * step;
    float lr2 = lr * lr;

    for (int j = 0; j < 8; j++) {
        int col = lane + 64 * j;
        float lc = -0.5f * (float)N + (float)col * step;
        float rr = sqrtf(lr2 + lc * lc);
        float h = (rr > 0.5f * (float)N)
                      ? 0.0f
                      : 0.5f * (1.0f + cosf(PI_F * rr * (1.0f / (0.5f * (float)N))));
        float v = (xrow[col] - mn) * h;
        int pos = bitrev9(col);
        re[ri][pos] = v;
        im[ri][pos] = 0.0f;
    }
    __syncthreads();

    for (int s = 1; s <= LOGN; s++) {
        int half = 1 << (s - 1);
        int tshift = LOGN - s;           // tw index = k * (N/2^s) = k << (LOGN - s)
        for (int q = 0; q < 4; q++) {
            int j = lane + 64 * q;       // butterfly id 0..255
            int k = j & (half - 1);
            int i0 = ((j >> (s - 1)) << s) + k;
            int i1 = i0 + half;
            float2 w = tw[k << tshift];
            float xr = re[ri][i1], xi = im[ri][i1];
            float tr = w.x * xr - w.y * xi;
            float ti = w.x * xi + w.y * xr;
            float ur = re[ri][i0], ui = im[ri][i0];
            re[ri][i0] = ur + tr; im[ri][i0] = ui + ti;
            re[ri][i1] = ur - tr; im[ri][i1] = ui - ti;
        }
        __syncthreads();
    }

    float2* orow = inter + ((size_t)bi * N + r) * N;
    for (int j = 0; j < 8; j++) {
        int col = lane + 64 * j;
        orow[col] = make_float2(re[ri][col], im[ri][col]);
    }
}

// ---------------- column FFT + |F|^2 accumulate (fftshifted) ----------------
// grid: (N/4 column-tiles, G batch groups); block loops over its images.
__global__ __launch_bounds__(256) void colfft_kernel(const float2* __restrict__ inter,
                                                     float* __restrict__ acc,
                                                     int nimg, int ngroups) {
    __shared__ float re[4][N];
    __shared__ float im[4][N];
    __shared__ float2 tw[N / 2];
    int t = threadIdx.x;
    if (t < N / 2) {
        float sv, cv;
        sincosf(-PI_F * (float)t * (1.0f / (float)(N / 2)), &sv, &cv);
        tw[t] = make_float2(cv, sv);
    }
    int ci   = t >> 6;
    int lane = t & 63;
    int col = blockIdx.x * 4 + ci;
    int g = blockIdx.y;
    int per = (nimg + ngroups - 1) / ngroups;
    int b0 = g * per;
    int b1 = min(nimg, b0 + per);

    float accu[8];
#pragma unroll
    for (int j = 0; j < 8; j++) accu[j] = 0.0f;

    for (int b = b0; b < b1; b++) {
        const float2* img = inter + (size_t)b * N * N;
        __syncthreads();   // prior iteration's reads done (and tw ready on first pass)
        for (int j = 0; j < 8; j++) {
            int row = lane + 64 * j;
            float2 v = img[(size_t)row * N + col];
            int pos = bitrev9(row);
            re[ci][pos] = v.x;
            im[ci][pos] = v.y;
        }
        __syncthreads();
        for (int s = 1; s <= LOGN; s++) {
            int half = 1 << (s - 1);
            int tshift = LOGN - s;
            for (int q = 0; q < 4; q++) {
                int j = lane + 64 * q;
                int k = j & (half - 1);
                int i0 = ((j >> (s - 1)) << s) + k;
                int i1 = i0 + half;
                float2 w = tw[k << tshift];
                float xr = re[ci][i1], xi = im[ci][i1];
                float tr = w.x * xr - w.y * xi;
                float ti = w.x * xi + w.y * xr;
                float ur = re[ci][i0], ui = im[ci][i0];
                re[ci][i0] = ur + tr; im[ci][i0] = ui + ti;
                re[ci][i1] = ur - tr; im[ci][i1] = ui - ti;
            }
            __syncthreads();
        }
#pragma unroll
        for (int j = 0; j < 8; j++) {
            int row = lane + 64 * j;
            float xr = re[ci][row], xi = im[ci][row];
            accu[j] += xr * xr + xi * xi;
        }
    }

    if (b1 > b0) {
        int sv = (col + N / 2) & (N - 1);
#pragma unroll
        for (int j = 0; j < 8; j++) {
            int row = lane + 64 * j;
            int su = (row + N / 2) & (N - 1);
            atomicAdd(&acc[su * N + sv], accu[j]);
        }
    }
}

// ---------------- finalize: nps2D + radial bin partial sums ----------------
__global__ __launch_bounds__(256) void finalize2d_kernel(const float* __restrict__ acc,
                                                         float* __restrict__ out2d,
                                                         float* __restrict__ bins) {
    __shared__ float lsum[NF];
    __shared__ float lcnt[NF];
    int t = threadIdx.x;
    for (int i = t; i < NF; i += 256) { lsum[i] = 0.0f; lcnt[i] = 0.0f; }
    __syncthreads();
    const float scale = (0.1f * 0.1f) / ((float)N * (float)N) / (float)NB;
    int idx = blockIdx.x * 256 + t;
    int stride = gridDim.x * 256;
    for (int p = idx; p < N * N; p += stride) {
        int i = p >> LOGN, j = p & (N - 1);
        float v = acc[p] * scale;
        out2d[p] = v;
        float xi = (float)(i - N / 2), yj = (float)(j - N / 2);
        int rad = (int)rintf(sqrtf(xi * xi + yj * yj));
        if (rad < NF) {
            atomicAdd(&lsum[rad], v);
            atomicAdd(&lcnt[rad], 1.0f);
        }
    }
    __syncthreads();
    for (int i = t; i < NF; i += 256) {
        if (lsum[i] != 0.0f || lcnt[i] != 0.0f) {
            atomicAdd(&bins[i], lsum[i]);
            atomicAdd(&bins[NF + 1 + i], lcnt[i]);
        }
    }
}

// ---------------- finalize: nps1D + f1D ----------------
__global__ void finalize1d_kernel(const float* __restrict__ bins, float* __restrict__ out) {
    int t = blockIdx.x * blockDim.x + threadIdx.x;
    if (t < NF) {
        out[t] = bins[t] / bins[NF + 1 + t];                       // nps1D
        out[NF + N * N + t] = (float)t * (5.0f / 256.0f);          // f1D, nyquist=5
    }
}

extern "C" void kernel_launch(void* const* d_in, const int* in_sizes, int n_in,
                              void* d_out, int out_size, void* d_ws, size_t ws_size,
                              hipStream_t stream) {
    const float* x = (const float*)d_in[0];
    float* out = (float*)d_out;
    char* ws = (char*)d_ws;

    float* acc  = (float*)ws;                                  // N*N floats
    float* mean = (float*)(ws + (size_t)N * N * sizeof(float)); // NB floats
    float* bins = mean + NB;                                    // 2*(NF+1) floats
    size_t off_inter = (size_t)N * N * sizeof(float) + NB * sizeof(float)
                       + 2 * (NF + 1) * sizeof(float);
    off_inter = (off_inter + 255) & ~(size_t)255;
    float2* inter = (float2*)(ws + off_inter);

    size_t cap = (ws_size > off_inter)
                     ? (ws_size - off_inter) / ((size_t)N * N * sizeof(float2))
                     : 0;
    int C = (int)(cap < (size_t)NB ? cap : (size_t)NB);
    if (C < 1) C = 1;  // assume ws is at least ~3 MB

    zero_kernel<<<dim3((N * N + 255) / 256), dim3(256), 0, stream>>>(acc, bins);
    mean_kernel<<<dim3(NB), dim3(256), 0, stream>>>(x, mean);

    for (int s = 0; s < NB; s += C) {
        int c = (NB - s) < C ? (NB - s) : C;
        rowfft_kernel<<<dim3(c * N / 4), dim3(256), 0, stream>>>(x, mean, inter, s);
        colfft_kernel<<<dim3(N / 4, 8), dim3(256), 0, stream>>>(inter, acc, c, 8);
    }

    finalize2d_kernel<<<dim3(256), dim3(256), 0, stream>>>(acc, out + NF, bins);
    finalize1d_kernel<<<dim3(2), dim3(256), 0, stream>>>(bins, out);
}

// Round 2
// 406.178 us; speedup vs baseline: 1.7839x; 1.7839x over previous
//
#include <hip/hip_runtime.h>

#define N 512
#define NF 257        // n_freq = N/2 + 1
#define NB 128        // batch
#define PI_F 3.14159265358979323846f
#define C_SQ2 0.70710678118654752440f

__device__ __forceinline__ float2 cmul(float2 a, float2 b) {
    return make_float2(a.x * b.x - a.y * b.y, a.x * b.y + a.y * b.x);
}
__device__ __forceinline__ void bf(float2& a, float2& b) {
    float2 t = b;
    b = make_float2(a.x - t.x, a.y - t.y);
    a = make_float2(a.x + t.x, a.y + t.y);
}
__device__ __forceinline__ void bf_tw(float2& a, float2& b, float2 w) {
    float2 t = cmul(b, w);
    b = make_float2(a.x - t.x, a.y - t.y);
    a = make_float2(a.x + t.x, a.y + t.y);
}
__device__ __forceinline__ void bf_ni(float2& a, float2& b) {   // tw = -i
    float2 t = make_float2(b.y, -b.x);
    b = make_float2(a.x - t.x, a.y - t.y);
    a = make_float2(a.x + t.x, a.y + t.y);
}
__device__ __forceinline__ void lds_fence() {
    asm volatile("s_waitcnt lgkmcnt(0)" ::: "memory");
}

// 512-pt FFT per wave (64 lanes x 8 float2 regs).
// Input: v[e] = x[brev9(8*l + e)] (bit-reversed load done by caller).
// Output: lane l holds X[64*t + l] in v[t] (natural order).
// lre/lim: per-wave LDS scratch, 576 floats each (padded i + (i>>3)).
__device__ __forceinline__ void fft512(float2 v[8], float* lre, float* lim, int l) {
    const float2 w64  = make_float2(C_SQ2, -C_SQ2);    // w^64  = e^{-i pi/4}
    const float2 w192 = make_float2(-C_SQ2, -C_SQ2);   // w^192 = e^{-3i pi/4}
    // ---- phase A: stages 1-3 (strides 1,2,4) in registers ----
    bf(v[0], v[1]); bf(v[2], v[3]); bf(v[4], v[5]); bf(v[6], v[7]);
    bf(v[0], v[2]); bf_ni(v[1], v[3]); bf(v[4], v[6]); bf_ni(v[5], v[7]);
    bf(v[0], v[4]); bf_tw(v[1], v[5], w64); bf_ni(v[2], v[6]); bf_tw(v[3], v[7], w192);
    // ---- transpose A->B: idx = 8l+e  ->  idx = 64g+8t+r ----
#pragma unroll
    for (int e = 0; e < 8; e++) { lre[9 * l + e] = v[e].x; lim[9 * l + e] = v[e].y; }
    lds_fence();
    int g = l >> 3, r = l & 7;
#pragma unroll
    for (int t = 0; t < 8; t++) {
        int p = 72 * g + 9 * t + r;
        v[t].x = lre[p]; v[t].y = lim[p];
    }
    // ---- phase B: stages 4-6 (strides 8,16,32) ----
    float sn, cs;
    sincosf(-(PI_F / 32.0f) * (float)r, &sn, &cs);
    float2 W1 = make_float2(cs, sn);        // w^(8r)
    float2 W2 = cmul(W1, W1);               // w^(16r)
    float2 W3 = cmul(W2, W2);               // w^(32r)
    float2 W2n = make_float2(W2.y, -W2.x);
    bf_tw(v[0], v[1], W3); bf_tw(v[2], v[3], W3); bf_tw(v[4], v[5], W3); bf_tw(v[6], v[7], W3);
    bf_tw(v[0], v[2], W2); bf_tw(v[1], v[3], W2n); bf_tw(v[4], v[6], W2); bf_tw(v[5], v[7], W2n);
    {
        float2 W1a = cmul(W1, w64);
        float2 W1n = make_float2(W1.y, -W1.x);
        float2 W1c = cmul(W1, w192);
        bf_tw(v[0], v[4], W1); bf_tw(v[1], v[5], W1a); bf_tw(v[2], v[6], W1n); bf_tw(v[3], v[7], W1c);
    }
    // ---- transpose B->C: -> lane c holds idx = 64t + c ----
#pragma unroll
    for (int t = 0; t < 8; t++) {
        int p = 72 * g + 9 * t + r;
        lre[p] = v[t].x; lim[p] = v[t].y;
    }
    lds_fence();
#pragma unroll
    for (int t = 0; t < 8; t++) {
        int p = 72 * t + l + (l >> 3);
        v[t].x = lre[p]; v[t].y = lim[p];
    }
    // ---- phase C: stages 7-9 (strides 64,128,256) ----
    sincosf(-(PI_F / 256.0f) * (float)l, &sn, &cs);
    float2 Wc = make_float2(cs, sn);        // w^c
    float2 w2 = cmul(Wc, Wc);               // w^(2c)
    float2 w4 = cmul(w2, w2);               // w^(4c)
    float2 w2n = make_float2(w2.y, -w2.x);
    bf_tw(v[0], v[1], w4); bf_tw(v[2], v[3], w4); bf_tw(v[4], v[5], w4); bf_tw(v[6], v[7], w4);
    bf_tw(v[0], v[2], w2); bf_tw(v[1], v[3], w2n); bf_tw(v[4], v[6], w2); bf_tw(v[5], v[7], w2n);
    {
        float2 Wca = cmul(Wc, w64);
        float2 Wcn = make_float2(Wc.y, -Wc.x);
        float2 Wcc = cmul(Wc, w192);
        bf_tw(v[0], v[4], Wc); bf_tw(v[1], v[5], Wca); bf_tw(v[2], v[6], Wcn); bf_tw(v[3], v[7], Wcc);
    }
}

// ---------------- zero accumulators ----------------
__global__ void zero_kernel(float* __restrict__ acc, float* __restrict__ bins) {
    int i = blockIdx.x * blockDim.x + threadIdx.x;
    if (i < N * N) acc[i] = 0.0f;
    if (i < 2 * (NF + 1)) bins[i] = 0.0f;
}

// ---------------- per-image mean ----------------
__global__ __launch_bounds__(256) void mean_kernel(const float* __restrict__ x,
                                                   float* __restrict__ mean) {
    int b = blockIdx.x;
    const float4* p = (const float4*)(x + (size_t)b * N * N);
    float s = 0.0f;
    for (int i = threadIdx.x; i < N * N / 4; i += 256) {
        float4 v = p[i];
        s += (v.x + v.y) + (v.z + v.w);
    }
    __shared__ float red[256];
    red[threadIdx.x] = s;
    __syncthreads();
    for (int off = 128; off > 0; off >>= 1) {
        if (threadIdx.x < off) red[threadIdx.x] += red[threadIdx.x + off];
        __syncthreads();
    }
    if (threadIdx.x == 0) mean[b] = red[0] * (1.0f / (float)(N * N));
}

// ---------------- row FFT: 2 real rows packed per wave, Hermitian half stored ----
// block = 512 threads = 8 waves = 16 rows of one image.
// inter layout: [img][col 0..256][row 0..511]  (transposed, coalesced for colfft)
__global__ __launch_bounds__(512) void rowfft_kernel(const float* __restrict__ x,
                                                     const float* __restrict__ mean,
                                                     float2* __restrict__ inter) {
    __shared__ float sm[9216];   // 8 waves * 1152 floats FFT scratch; reused as 2*[16][265] tile
    int tid = threadIdx.x;
    int w = tid >> 6, l = tid & 63;
    int img = blockIdx.x >> 5;
    int rowbase = (blockIdx.x & 31) << 4;
    int r1 = rowbase + 2 * w, r2 = r1 + 1;
    float mn = mean[img];
    const float* x1 = x + ((size_t)img * N + r1) * N;
    const float* x2 = x1 + N;

    const float step = (float)N / (float)(N - 1);
    float a1 = -0.5f * (float)N + (float)r1 * step;
    float a2 = -0.5f * (float)N + (float)r2 * step;
    float a1s = a1 * a1, a2s = a2 * a2;

    float2 v[8];
    int rl = __brev((unsigned)l) >> 26;
#pragma unroll
    for (int e = 0; e < 8; e++) {
        int src = (int)((__brev((unsigned)e) >> 29) << 6) + rl;
        float lc = -0.5f * (float)N + (float)src * step;
        float lc2 = lc * lc;
        float rr1 = sqrtf(a1s + lc2), rr2 = sqrtf(a2s + lc2);
        float h1 = (rr1 > 256.0f) ? 0.0f : 0.5f * (1.0f + cosf(PI_F * rr1 * (1.0f / 256.0f)));
        float h2 = (rr2 > 256.0f) ? 0.0f : 0.5f * (1.0f + cosf(PI_F * rr2 * (1.0f / 256.0f)));
        v[e].x = (x1[src] - mn) * h1;
        v[e].y = (x2[src] - mn) * h2;
    }

    float* lre = sm + w * 1152;
    float* lim = lre + 576;
    fft512(v, lre, lim, l);
    __syncthreads();   // all waves done with FFT scratch before tile reuse

    // unpack packed rows: R1 = (Z + conj(Zflip))/2, R2 = -i(Z - conj(Zflip))/2
    float* tre = sm;            // [16][265]
    float* tim = sm + 4240;
    int lr0 = 2 * w, lr1 = lr0 + 1;
    int sl = (64 - l) & 63;
#pragma unroll
    for (int t = 0; t <= 4; t++) {
        float2 a = v[7 - t];
        float zfx = __shfl(a.x, sl);
        float zfy = __shfl(a.y, sl);
        if (l == 0) { float2 o = v[(8 - t) & 7]; zfx = o.x; zfy = o.y; }
        float2 z = v[t];
        int col = 64 * t + l;
        if (col < NF) {
            tre[lr0 * 265 + col] = 0.5f * (z.x + zfx);
            tim[lr0 * 265 + col] = 0.5f * (z.y - zfy);
            tre[lr1 * 265 + col] = 0.5f * (z.y + zfy);
            tim[lr1 * 265 + col] = 0.5f * (zfx - z.x);
        }
    }
    __syncthreads();

    // coalesced transposed write: 16 consecutive rows per column
    int c0 = tid >> 4, rr = tid & 15;
#pragma unroll
    for (int it = 0; it < 9; it++) {
        int c = it * 32 + c0;
        if (c < NF) {
            float2 val = make_float2(tre[rr * 265 + c], tim[rr * 265 + c]);
            inter[((size_t)img * NF + c) * N + rowbase + rr] = val;
        }
    }
}

// ---------------- column FFT + |F|^2 accumulate (fftshifted, transposed acc) ----
// block = 512 threads = 8 waves = 8 columns; loops over 8 images; grid (33, 16).
__global__ __launch_bounds__(512) void colfft_kernel(const float2* __restrict__ inter,
                                                     float* __restrict__ accT) {
    __shared__ float sm[9216];
    int tid = threadIdx.x;
    int w = tid >> 6, l = tid & 63;
    int col = blockIdx.x * 8 + w;
    int colc = col < NF ? col : NF - 1;
    int b0 = blockIdx.y * 8;
    float* lre = sm + w * 1152;
    float* lim = lre + 576;
    int rl = __brev((unsigned)l) >> 26;

    float pw[8];
#pragma unroll
    for (int t = 0; t < 8; t++) pw[t] = 0.0f;

    for (int bi = 0; bi < 8; bi++) {
        const float2* base = inter + ((size_t)(b0 + bi) * NF + colc) * N;
        float2 v[8];
#pragma unroll
        for (int e = 0; e < 8; e++)
            v[e] = base[(int)((__brev((unsigned)e) >> 29) << 6) + rl];
        fft512(v, lre, lim, l);
#pragma unroll
        for (int t = 0; t < 8; t++)
            pw[t] += v[t].x * v[t].x + v[t].y * v[t].y;
    }

    if (col < NF) {
        int sv = (col + 256) & 511;
#pragma unroll
        for (int t = 0; t < 8; t++) {
            int k = 64 * t + l;
            int su = (k + 256) & 511;
            atomicAdd(&accT[(size_t)sv * N + su], pw[t]);
        }
        if (col >= 1 && col <= 255) {   // Hermitian mirror: P(512-k, 512-col) = P(k, col)
            int sv2 = (768 - col) & 511;
#pragma unroll
            for (int t = 0; t < 8; t++) {
                int k = 64 * t + l;
                int su2 = (768 - k) & 511;
                atomicAdd(&accT[(size_t)sv2 * N + su2], pw[t]);
            }
        }
    }
}

// ---------------- finalize: nps2D + radial bin partial sums ----------------
__global__ __launch_bounds__(256) void finalize2d_kernel(const float* __restrict__ accT,
                                                         float* __restrict__ out2d,
                                                         float* __restrict__ bins) {
    __shared__ float lsum[NF];
    __shared__ float lcnt[NF];
    int t = threadIdx.x;
    for (int i = t; i < NF; i += 256) { lsum[i] = 0.0f; lcnt[i] = 0.0f; }
    __syncthreads();
    const float scale = (0.1f * 0.1f) / ((float)N * (float)N) / (float)NB;
    int idx = blockIdx.x * 256 + t;
    int stride = gridDim.x * 256;
    for (int p = idx; p < N * N; p += stride) {
        int i = p >> 9, j = p & (N - 1);
        float v = accT[(size_t)j * N + i] * scale;   // acc stored transposed
        out2d[p] = v;
        float xi = (float)(i - N / 2), yj = (float)(j - N / 2);
        int rad = (int)rintf(sqrtf(xi * xi + yj * yj));
        if (rad < NF) {
            atomicAdd(&lsum[rad], v);
            atomicAdd(&lcnt[rad], 1.0f);
        }
    }
    __syncthreads();
    for (int i = t; i < NF; i += 256) {
        if (lsum[i] != 0.0f || lcnt[i] != 0.0f) {
            atomicAdd(&bins[i], lsum[i]);
            atomicAdd(&bins[NF + 1 + i], lcnt[i]);
        }
    }
}

// ---------------- finalize: nps1D + f1D ----------------
__global__ void finalize1d_kernel(const float* __restrict__ bins, float* __restrict__ out) {
    int t = blockIdx.x * blockDim.x + threadIdx.x;
    if (t < NF) {
        out[t] = bins[t] / bins[NF + 1 + t];                 // nps1D
        out[NF + N * N + t] = (float)t * (5.0f / 256.0f);    // f1D (nyquist = 5)
    }
}

extern "C" void kernel_launch(void* const* d_in, const int* in_sizes, int n_in,
                              void* d_out, int out_size, void* d_ws, size_t ws_size,
                              hipStream_t stream) {
    const float* x = (const float*)d_in[0];
    float* out = (float*)d_out;
    char* ws = (char*)d_ws;

    float* accT = (float*)ws;                                    // N*N floats (transposed)
    float* mean = (float*)(ws + (size_t)N * N * sizeof(float));  // NB floats
    float* bins = mean + NB;                                     // 2*(NF+1) floats
    size_t off_inter = (size_t)N * N * sizeof(float) + NB * sizeof(float)
                       + 2 * (NF + 1) * sizeof(float);
    off_inter = (off_inter + 255) & ~(size_t)255;
    float2* inter = (float2*)(ws + off_inter);   // [NB][NF][N] float2 = 134.7 MB

    zero_kernel<<<dim3((N * N + 255) / 256), dim3(256), 0, stream>>>(accT, bins);
    mean_kernel<<<dim3(NB), dim3(256), 0, stream>>>(x, mean);
    rowfft_kernel<<<dim3(NB * 32), dim3(512), 0, stream>>>(x, mean, inter);
    colfft_kernel<<<dim3(33, 16), dim3(512), 0, stream>>>(inter, accT);
    finalize2d_kernel<<<dim3(256), dim3(256), 0, stream>>>(accT, out + NF, bins);
    finalize1d_kernel<<<dim3(2), dim3(256), 0, stream>>>(bins, out);
}

// Round 3
// 308.002 us; speedup vs baseline: 2.3525x; 1.3188x over previous
//
#include <hip/hip_runtime.h>

#define N 512
#define NF 257        // n_freq = N/2 + 1
#define NB 128        // batch
#define PI_F 3.14159265358979323846f
#define C_SQ2 0.70710678118654752440f

__device__ __forceinline__ float2 cmul(float2 a, float2 b) {
    return make_float2(a.x * b.x - a.y * b.y, a.x * b.y + a.y * b.x);
}
__device__ __forceinline__ void bf(float2& a, float2& b) {
    float2 t = b;
    b = make_float2(a.x - t.x, a.y - t.y);
    a = make_float2(a.x + t.x, a.y + t.y);
}
__device__ __forceinline__ void bf_tw(float2& a, float2& b, float2 w) {
    float2 t = cmul(b, w);
    b = make_float2(a.x - t.x, a.y - t.y);
    a = make_float2(a.x + t.x, a.y + t.y);
}
__device__ __forceinline__ void bf_ni(float2& a, float2& b) {   // tw = -i
    float2 t = make_float2(b.y, -b.x);
    b = make_float2(a.x - t.x, a.y - t.y);
    a = make_float2(a.x + t.x, a.y + t.y);
}
__device__ __forceinline__ void lds_fence() {
    asm volatile("s_waitcnt lgkmcnt(0)" ::: "memory");
}

// 512-pt FFT per wave (64 lanes x 8 float2 regs).
// Input: v[e] = x[brev9(8*l + e)] (bit-reversed load done by caller).
// Output: lane l holds X[64*t + l] in v[t] (natural order).
// lre/lim: per-wave LDS scratch, 576 floats each (padded i + (i>>3)).
__device__ __forceinline__ void fft512(float2 v[8], float* lre, float* lim, int l) {
    const float2 w64  = make_float2(C_SQ2, -C_SQ2);    // w^64  = e^{-i pi/4}
    const float2 w192 = make_float2(-C_SQ2, -C_SQ2);   // w^192 = e^{-3i pi/4}
    // ---- phase A: stages 1-3 (strides 1,2,4) in registers ----
    bf(v[0], v[1]); bf(v[2], v[3]); bf(v[4], v[5]); bf(v[6], v[7]);
    bf(v[0], v[2]); bf_ni(v[1], v[3]); bf(v[4], v[6]); bf_ni(v[5], v[7]);
    bf(v[0], v[4]); bf_tw(v[1], v[5], w64); bf_ni(v[2], v[6]); bf_tw(v[3], v[7], w192);
    // ---- transpose A->B: idx = 8l+e  ->  idx = 64g+8t+r ----
#pragma unroll
    for (int e = 0; e < 8; e++) { lre[9 * l + e] = v[e].x; lim[9 * l + e] = v[e].y; }
    lds_fence();
    int g = l >> 3, r = l & 7;
#pragma unroll
    for (int t = 0; t < 8; t++) {
        int p = 72 * g + 9 * t + r;
        v[t].x = lre[p]; v[t].y = lim[p];
    }
    // ---- phase B: stages 4-6 (strides 8,16,32) ----
    float sn, cs;
    sincosf(-(PI_F / 32.0f) * (float)r, &sn, &cs);
    float2 W1 = make_float2(cs, sn);        // w^(8r)
    float2 W2 = cmul(W1, W1);               // w^(16r)
    float2 W3 = cmul(W2, W2);               // w^(32r)
    float2 W2n = make_float2(W2.y, -W2.x);
    bf_tw(v[0], v[1], W3); bf_tw(v[2], v[3], W3); bf_tw(v[4], v[5], W3); bf_tw(v[6], v[7], W3);
    bf_tw(v[0], v[2], W2); bf_tw(v[1], v[3], W2n); bf_tw(v[4], v[6], W2); bf_tw(v[5], v[7], W2n);
    {
        float2 W1a = cmul(W1, w64);
        float2 W1n = make_float2(W1.y, -W1.x);
        float2 W1c = cmul(W1, w192);
        bf_tw(v[0], v[4], W1); bf_tw(v[1], v[5], W1a); bf_tw(v[2], v[6], W1n); bf_tw(v[3], v[7], W1c);
    }
    // ---- transpose B->C: -> lane c holds idx = 64t + c ----
#pragma unroll
    for (int t = 0; t < 8; t++) {
        int p = 72 * g + 9 * t + r;
        lre[p] = v[t].x; lim[p] = v[t].y;
    }
    lds_fence();
#pragma unroll
    for (int t = 0; t < 8; t++) {
        int p = 72 * t + l + (l >> 3);
        v[t].x = lre[p]; v[t].y = lim[p];
    }
    // ---- phase C: stages 7-9 (strides 64,128,256) ----
    sincosf(-(PI_F / 256.0f) * (float)l, &sn, &cs);
    float2 Wc = make_float2(cs, sn);        // w^c
    float2 w2 = cmul(Wc, Wc);               // w^(2c)
    float2 w4 = cmul(w2, w2);               // w^(4c)
    float2 w2n = make_float2(w2.y, -w2.x);
    bf_tw(v[0], v[1], w4); bf_tw(v[2], v[3], w4); bf_tw(v[4], v[5], w4); bf_tw(v[6], v[7], w4);
    bf_tw(v[0], v[2], w2); bf_tw(v[1], v[3], w2n); bf_tw(v[4], v[6], w2); bf_tw(v[5], v[7], w2n);
    {
        float2 Wca = cmul(Wc, w64);
        float2 Wcn = make_float2(Wc.y, -Wc.x);
        float2 Wcc = cmul(Wc, w192);
        bf_tw(v[0], v[4], Wc); bf_tw(v[1], v[5], Wca); bf_tw(v[2], v[6], Wcn); bf_tw(v[3], v[7], Wcc);
    }
}

// ---------------- zero accumulators ----------------
__global__ void zero_kernel(float* __restrict__ acc, float* __restrict__ bins,
                            float* __restrict__ meanacc) {
    int i = blockIdx.x * blockDim.x + threadIdx.x;
    if (i < N * N) acc[i] = 0.0f;
    if (i < 2 * (NF + 1)) bins[i] = 0.0f;
    if (i < NB) meanacc[i] = 0.0f;
}

// ---------------- per-image partial sums (2048 blocks, full GPU) ----------------
// grid (16 slices, NB images); each block sums a 16384-float slice.
__global__ __launch_bounds__(256) void meanpart_kernel(const float* __restrict__ x,
                                                       float* __restrict__ meanacc) {
    int b = blockIdx.y;
    const float4* p = (const float4*)(x + (size_t)b * N * N) + blockIdx.x * 4096;
    float s = 0.0f;
#pragma unroll
    for (int it = 0; it < 16; it++) {
        float4 v = p[it * 256 + threadIdx.x];
        s += (v.x + v.y) + (v.z + v.w);
    }
#pragma unroll
    for (int off = 32; off > 0; off >>= 1) s += __shfl_down(s, off);
    __shared__ float red[4];
    if ((threadIdx.x & 63) == 0) red[threadIdx.x >> 6] = s;
    __syncthreads();
    if (threadIdx.x == 0)
        atomicAdd(meanacc + b, (red[0] + red[1]) + (red[2] + red[3]));
}

// ---------------- row FFT: 2 real rows packed per wave, Hermitian half stored ----
// block = 512 threads = 8 waves = 16 rows of one image.
// inter layout: [img][col 0..256][row 0..511]  (transposed, coalesced for colfft)
__global__ __launch_bounds__(512) void rowfft_kernel(const float* __restrict__ x,
                                                     const float* __restrict__ meanacc,
                                                     float2* __restrict__ inter) {
    __shared__ float sm[9216];   // 8 waves * 1152 floats FFT scratch; reused as 2*[16][265] tile
    int tid = threadIdx.x;
    int w = tid >> 6, l = tid & 63;
    int img = blockIdx.x >> 5;
    int rowbase = (blockIdx.x & 31) << 4;
    int r1 = rowbase + 2 * w, r2 = r1 + 1;
    float mn = meanacc[img] * (1.0f / ((float)N * (float)N));
    const float* x1 = x + ((size_t)img * N + r1) * N;
    const float* x2 = x1 + N;

    const float step = (float)N / (float)(N - 1);
    float a1 = -0.5f * (float)N + (float)r1 * step;
    float a2 = -0.5f * (float)N + (float)r2 * step;
    float a1s = a1 * a1, a2s = a2 * a2;

    float2 v[8];
    int rl = __brev((unsigned)l) >> 26;
#pragma unroll
    for (int e = 0; e < 8; e++) {
        int src = (int)((__brev((unsigned)e) >> 29) << 6) + rl;
        float lc = -0.5f * (float)N + (float)src * step;
        float lc2 = lc * lc;
        float rr1 = sqrtf(a1s + lc2), rr2 = sqrtf(a2s + lc2);
        float h1 = (rr1 > 256.0f) ? 0.0f : 0.5f * (1.0f + cosf(PI_F * rr1 * (1.0f / 256.0f)));
        float h2 = (rr2 > 256.0f) ? 0.0f : 0.5f * (1.0f + cosf(PI_F * rr2 * (1.0f / 256.0f)));
        v[e].x = (x1[src] - mn) * h1;
        v[e].y = (x2[src] - mn) * h2;
    }

    float* lre = sm + w * 1152;
    float* lim = lre + 576;
    fft512(v, lre, lim, l);
    __syncthreads();   // all waves done with FFT scratch before tile reuse

    // unpack packed rows: R1 = (Z + conj(Zflip))/2, R2 = -i(Z - conj(Zflip))/2
    float* tre = sm;            // [16][265]
    float* tim = sm + 4240;
    int lr0 = 2 * w, lr1 = lr0 + 1;
    int sl = (64 - l) & 63;
#pragma unroll
    for (int t = 0; t <= 4; t++) {
        float2 a = v[7 - t];
        float zfx = __shfl(a.x, sl);
        float zfy = __shfl(a.y, sl);
        if (l == 0) { float2 o = v[(8 - t) & 7]; zfx = o.x; zfy = o.y; }
        float2 z = v[t];
        int col = 64 * t + l;
        if (col < NF) {
            tre[lr0 * 265 + col] = 0.5f * (z.x + zfx);
            tim[lr0 * 265 + col] = 0.5f * (z.y - zfy);
            tre[lr1 * 265 + col] = 0.5f * (z.y + zfy);
            tim[lr1 * 265 + col] = 0.5f * (zfx - z.x);
        }
    }
    __syncthreads();

    // coalesced transposed write: 16 consecutive rows per column
    int c0 = tid >> 4, rr = tid & 15;
#pragma unroll
    for (int it = 0; it < 9; it++) {
        int c = it * 32 + c0;
        if (c < NF) {
            float2 val = make_float2(tre[rr * 265 + c], tim[rr * 265 + c]);
            inter[((size_t)img * NF + c) * N + rowbase + rr] = val;
        }
    }
}

// ---------------- column FFT + |F|^2 accumulate (fftshifted, transposed acc) ----
// block = 512 threads = 8 waves = 8 columns; loops over 8 images; grid (33, 16).
__global__ __launch_bounds__(512) void colfft_kernel(const float2* __restrict__ inter,
                                                     float* __restrict__ accT) {
    __shared__ float sm[9216];
    int tid = threadIdx.x;
    int w = tid >> 6, l = tid & 63;
    int col = blockIdx.x * 8 + w;
    int colc = col < NF ? col : NF - 1;
    int b0 = blockIdx.y * 8;
    float* lre = sm + w * 1152;
    float* lim = lre + 576;
    int rl = __brev((unsigned)l) >> 26;

    float pw[8];
#pragma unroll
    for (int t = 0; t < 8; t++) pw[t] = 0.0f;

    for (int bi = 0; bi < 8; bi++) {
        const float2* base = inter + ((size_t)(b0 + bi) * NF + colc) * N;
        float2 v[8];
#pragma unroll
        for (int e = 0; e < 8; e++)
            v[e] = base[(int)((__brev((unsigned)e) >> 29) << 6) + rl];
        fft512(v, lre, lim, l);
#pragma unroll
        for (int t = 0; t < 8; t++)
            pw[t] += v[t].x * v[t].x + v[t].y * v[t].y;
    }

    if (col < NF) {
        int sv = (col + 256) & 511;
#pragma unroll
        for (int t = 0; t < 8; t++) {
            int k = 64 * t + l;
            int su = (k + 256) & 511;
            atomicAdd(&accT[(size_t)sv * N + su], pw[t]);
        }
        if (col >= 1 && col <= 255) {   // Hermitian mirror: P(512-k, 512-col) = P(k, col)
            int sv2 = (768 - col) & 511;
#pragma unroll
            for (int t = 0; t < 8; t++) {
                int k = 64 * t + l;
                int su2 = (768 - k) & 511;
                atomicAdd(&accT[(size_t)sv2 * N + su2], pw[t]);
            }
        }
    }
}

// ---------------- finalize: nps2D + radial bin partial sums ----------------
__global__ __launch_bounds__(256) void finalize2d_kernel(const float* __restrict__ accT,
                                                         float* __restrict__ out2d,
                                                         float* __restrict__ bins) {
    __shared__ float lsum[NF];
    __shared__ float lcnt[NF];
    int t = threadIdx.x;
    for (int i = t; i < NF; i += 256) { lsum[i] = 0.0f; lcnt[i] = 0.0f; }
    __syncthreads();
    const float scale = (0.1f * 0.1f) / ((float)N * (float)N) / (float)NB;
    int idx = blockIdx.x * 256 + t;
    int stride = gridDim.x * 256;
    for (int p = idx; p < N * N; p += stride) {
        int i = p >> 9, j = p & (N - 1);
        float v = accT[(size_t)j * N + i] * scale;   // acc stored transposed
        out2d[p] = v;
        float xi = (float)(i - N / 2), yj = (float)(j - N / 2);
        int rad = (int)rintf(sqrtf(xi * xi + yj * yj));
        if (rad < NF) {
            atomicAdd(&lsum[rad], v);
            atomicAdd(&lcnt[rad], 1.0f);
        }
    }
    __syncthreads();
    for (int i = t; i < NF; i += 256) {
        if (lsum[i] != 0.0f || lcnt[i] != 0.0f) {
            atomicAdd(&bins[i], lsum[i]);
            atomicAdd(&bins[NF + 1 + i], lcnt[i]);
        }
    }
}

// ---------------- finalize: nps1D + f1D ----------------
__global__ void finalize1d_kernel(const float* __restrict__ bins, float* __restrict__ out) {
    int t = blockIdx.x * blockDim.x + threadIdx.x;
    if (t < NF) {
        out[t] = bins[t] / bins[NF + 1 + t];                 // nps1D
        out[NF + N * N + t] = (float)t * (5.0f / 256.0f);    // f1D (nyquist = 5)
    }
}

extern "C" void kernel_launch(void* const* d_in, const int* in_sizes, int n_in,
                              void* d_out, int out_size, void* d_ws, size_t ws_size,
                              hipStream_t stream) {
    const float* x = (const float*)d_in[0];
    float* out = (float*)d_out;
    char* ws = (char*)d_ws;

    float* accT    = (float*)ws;                                    // N*N floats (transposed)
    float* meanacc = (float*)(ws + (size_t)N * N * sizeof(float));  // NB floats
    float* bins    = meanacc + NB;                                  // 2*(NF+1) floats
    size_t off_inter = (size_t)N * N * sizeof(float) + NB * sizeof(float)
                       + 2 * (NF + 1) * sizeof(float);
    off_inter = (off_inter + 255) & ~(size_t)255;
    float2* inter = (float2*)(ws + off_inter);   // [NB][NF][N] float2 = 134.7 MB

    zero_kernel<<<dim3((N * N + 255) / 256), dim3(256), 0, stream>>>(accT, bins, meanacc);
    meanpart_kernel<<<dim3(16, NB), dim3(256), 0, stream>>>(x, meanacc);
    rowfft_kernel<<<dim3(NB * 32), dim3(512), 0, stream>>>(x, meanacc, inter);
    colfft_kernel<<<dim3(33, 16), dim3(512), 0, stream>>>(inter, accT);
    finalize2d_kernel<<<dim3(256), dim3(256), 0, stream>>>(accT, out + NF, bins);
    finalize1d_kernel<<<dim3(2), dim3(256), 0, stream>>>(bins, out);
}

// Round 5
// 276.497 us; speedup vs baseline: 2.6206x; 1.1139x over previous
//
#include <hip/hip_runtime.h>

#define N 512
#define NF 257        // n_freq = N/2 + 1
#define NB 128        // batch
#define PI_F 3.14159265358979323846f
#define C_SQ2 0.70710678118654752440f

__device__ __forceinline__ float2 cmul(float2 a, float2 b) {
    return make_float2(a.x * b.x - a.y * b.y, a.x * b.y + a.y * b.x);
}
__device__ __forceinline__ void bf(float2& a, float2& b) {
    float2 t = b;
    b = make_float2(a.x - t.x, a.y - t.y);
    a = make_float2(a.x + t.x, a.y + t.y);
}
__device__ __forceinline__ void bf_tw(float2& a, float2& b, float2 w) {
    float2 t = cmul(b, w);
    b = make_float2(a.x - t.x, a.y - t.y);
    a = make_float2(a.x + t.x, a.y + t.y);
}
__device__ __forceinline__ void bf_ni(float2& a, float2& b) {   // tw = -i
    float2 t = make_float2(b.y, -b.x);
    b = make_float2(a.x - t.x, a.y - t.y);
    a = make_float2(a.x + t.x, a.y + t.y);
}
__device__ __forceinline__ void lds_fence() {
    asm volatile("s_waitcnt lgkmcnt(0)" ::: "memory");
}

// 512-pt FFT per wave (64 lanes x 8 float2 regs).
// Input: v[e] = x[brev9(8*l + e)] (bit-reversed load done by caller).
// Output: lane l holds X[64*t + l] in v[t] (natural order).
// lre/lim: per-wave LDS scratch, 576 floats each (padded i + (i>>3)).
__device__ __forceinline__ void fft512(float2 v[8], float* lre, float* lim, int l) {
    const float2 w64  = make_float2(C_SQ2, -C_SQ2);    // w^64  = e^{-i pi/4}
    const float2 w192 = make_float2(-C_SQ2, -C_SQ2);   // w^192 = e^{-3i pi/4}
    // ---- phase A: stages 1-3 (strides 1,2,4) in registers ----
    bf(v[0], v[1]); bf(v[2], v[3]); bf(v[4], v[5]); bf(v[6], v[7]);
    bf(v[0], v[2]); bf_ni(v[1], v[3]); bf(v[4], v[6]); bf_ni(v[5], v[7]);
    bf(v[0], v[4]); bf_tw(v[1], v[5], w64); bf_ni(v[2], v[6]); bf_tw(v[3], v[7], w192);
    // ---- transpose A->B: idx = 8l+e  ->  idx = 64g+8t+r ----
#pragma unroll
    for (int e = 0; e < 8; e++) { lre[9 * l + e] = v[e].x; lim[9 * l + e] = v[e].y; }
    lds_fence();
    int g = l >> 3, r = l & 7;
#pragma unroll
    for (int t = 0; t < 8; t++) {
        int p = 72 * g + 9 * t + r;
        v[t].x = lre[p]; v[t].y = lim[p];
    }
    // ---- phase B: stages 4-6 (strides 8,16,32) ----
    float sn, cs;
    __sincosf(-(PI_F / 32.0f) * (float)r, &sn, &cs);
    float2 W1 = make_float2(cs, sn);        // w^(8r)
    float2 W2 = cmul(W1, W1);               // w^(16r)
    float2 W3 = cmul(W2, W2);               // w^(32r)
    float2 W2n = make_float2(W2.y, -W2.x);
    bf_tw(v[0], v[1], W3); bf_tw(v[2], v[3], W3); bf_tw(v[4], v[5], W3); bf_tw(v[6], v[7], W3);
    bf_tw(v[0], v[2], W2); bf_tw(v[1], v[3], W2n); bf_tw(v[4], v[6], W2); bf_tw(v[5], v[7], W2n);
    {
        float2 W1a = cmul(W1, w64);
        float2 W1n = make_float2(W1.y, -W1.x);
        float2 W1c = cmul(W1, w192);
        bf_tw(v[0], v[4], W1); bf_tw(v[1], v[5], W1a); bf_tw(v[2], v[6], W1n); bf_tw(v[3], v[7], W1c);
    }
    // ---- transpose B->C: -> lane c holds idx = 64t + c ----
#pragma unroll
    for (int t = 0; t < 8; t++) {
        int p = 72 * g + 9 * t + r;
        lre[p] = v[t].x; lim[p] = v[t].y;
    }
    lds_fence();
#pragma unroll
    for (int t = 0; t < 8; t++) {
        int p = 72 * t + l + (l >> 3);
        v[t].x = lre[p]; v[t].y = lim[p];
    }
    // ---- phase C: stages 7-9 (strides 64,128,256) ----
    __sincosf(-(PI_F / 256.0f) * (float)l, &sn, &cs);
    float2 Wc = make_float2(cs, sn);        // w^c
    float2 w2 = cmul(Wc, Wc);               // w^(2c)
    float2 w4 = cmul(w2, w2);               // w^(4c)
    float2 w2n = make_float2(w2.y, -w2.x);
    bf_tw(v[0], v[1], w4); bf_tw(v[2], v[3], w4); bf_tw(v[4], v[5], w4); bf_tw(v[6], v[7], w4);
    bf_tw(v[0], v[2], w2); bf_tw(v[1], v[3], w2n); bf_tw(v[4], v[6], w2); bf_tw(v[5], v[7], w2n);
    {
        float2 Wca = cmul(Wc, w64);
        float2 Wcn = make_float2(Wc.y, -Wc.x);
        float2 Wcc = cmul(Wc, w192);
        bf_tw(v[0], v[4], Wc); bf_tw(v[1], v[5], Wca); bf_tw(v[2], v[6], Wcn); bf_tw(v[3], v[7], Wcc);
    }
}

// ---------------- zero accumulators ----------------
__global__ void zero_kernel(float* __restrict__ acc, float* __restrict__ bins,
                            float* __restrict__ meanacc) {
    int i = blockIdx.x * blockDim.x + threadIdx.x;
    if (i < N * N) acc[i] = 0.0f;
    if (i < 2 * (NF + 1)) bins[i] = 0.0f;
    if (i < NB) meanacc[i] = 0.0f;
}

// ---------------- rowFFT of the Hann window itself (once per launch) ----------
// Hrow layout: [col 0..256][row 0..511] float2, same as one image of inter.
__global__ __launch_bounds__(512) void hannfft_kernel(float2* __restrict__ Hrow) {
    __shared__ float sm[9216];
    int tid = threadIdx.x;
    int w = tid >> 6, l = tid & 63;
    int rowbase = blockIdx.x << 4;
    int r1 = rowbase + 2 * w, r2 = r1 + 1;

    const float step = (float)N / (float)(N - 1);
    float a1 = -0.5f * (float)N + (float)r1 * step;
    float a2 = -0.5f * (float)N + (float)r2 * step;
    float a1s = a1 * a1, a2s = a2 * a2;

    float2 v[8];
    int rl = __brev((unsigned)l) >> 26;
#pragma unroll
    for (int e = 0; e < 8; e++) {
        int src = (int)((__brev((unsigned)e) >> 29) << 6) + rl;
        float lc = -0.5f * (float)N + (float)src * step;
        float lc2 = lc * lc;
        float rr1 = sqrtf(a1s + lc2), rr2 = sqrtf(a2s + lc2);
        float h1 = (rr1 > 256.0f) ? 0.0f : 0.5f * (1.0f + cosf(PI_F * rr1 * (1.0f / 256.0f)));
        float h2 = (rr2 > 256.0f) ? 0.0f : 0.5f * (1.0f + cosf(PI_F * rr2 * (1.0f / 256.0f)));
        v[e].x = h1;
        v[e].y = h2;
    }

    float* lre = sm + w * 1152;
    float* lim = lre + 576;
    fft512(v, lre, lim, l);
    __syncthreads();

    float* tre = sm;            // [16][265]
    float* tim = sm + 4240;
    int lr0 = 2 * w, lr1 = lr0 + 1;
    int sl = (64 - l) & 63;
#pragma unroll
    for (int t = 0; t <= 4; t++) {
        float2 a = v[7 - t];
        float zfx = __shfl(a.x, sl);
        float zfy = __shfl(a.y, sl);
        if (l == 0) { float2 o = v[(8 - t) & 7]; zfx = o.x; zfy = o.y; }
        float2 z = v[t];
        int col = 64 * t + l;
        if (col < NF) {
            tre[lr0 * 265 + col] = 0.5f * (z.x + zfx);
            tim[lr0 * 265 + col] = 0.5f * (z.y - zfy);
            tre[lr1 * 265 + col] = 0.5f * (z.y + zfy);
            tim[lr1 * 265 + col] = 0.5f * (zfx - z.x);
        }
    }
    __syncthreads();

    int c0 = tid >> 4, rr = tid & 15;
#pragma unroll
    for (int it = 0; it < 9; it++) {
        int c = it * 32 + c0;
        if (c < NF) {
            float2 val = make_float2(tre[rr * 265 + c], tim[rr * 265 + c]);
            Hrow[(size_t)c * N + rowbase + rr] = val;
        }
    }
}

// ---------------- row FFT: 2 real rows packed per wave, Hermitian half stored ----
// block = 512 threads = 8 waves = 16 rows of one image. No mean subtraction here
// (handled in colfft via linearity); accumulates raw row sums into meanacc.
__global__ __launch_bounds__(512) void rowfft_kernel(const float* __restrict__ x,
                                                     float* __restrict__ meanacc,
                                                     float2* __restrict__ inter) {
    __shared__ float sm[9216];   // 8 waves * 1152 floats FFT scratch; reused as 2*[16][265] tile
    __shared__ float redsum[8];
    int tid = threadIdx.x;
    int w = tid >> 6, l = tid & 63;
    int img = blockIdx.x >> 5;
    int rowbase = (blockIdx.x & 31) << 4;
    int r1 = rowbase + 2 * w, r2 = r1 + 1;
    const float* x1 = x + ((size_t)img * N + r1) * N;
    const float* x2 = x1 + N;

    const float step = (float)N / (float)(N - 1);
    float a1 = -0.5f * (float)N + (float)r1 * step;
    float a2 = -0.5f * (float)N + (float)r2 * step;
    float a1s = a1 * a1, a2s = a2 * a2;

    float2 v[8];
    float rsum = 0.0f;
    int rl = __brev((unsigned)l) >> 26;
#pragma unroll
    for (int e = 0; e < 8; e++) {
        int src = (int)((__brev((unsigned)e) >> 29) << 6) + rl;
        float lc = -0.5f * (float)N + (float)src * step;
        float lc2 = lc * lc;
        float rr1 = sqrtf(a1s + lc2), rr2 = sqrtf(a2s + lc2);
        float h1 = (rr1 > 256.0f) ? 0.0f : 0.5f * (1.0f + __cosf(rr1 * (PI_F / 256.0f)));
        float h2 = (rr2 > 256.0f) ? 0.0f : 0.5f * (1.0f + __cosf(rr2 * (PI_F / 256.0f)));
        float xv1 = x1[src], xv2 = x2[src];
        rsum += xv1 + xv2;
        v[e].x = xv1 * h1;
        v[e].y = xv2 * h2;
    }
#pragma unroll
    for (int off = 32; off > 0; off >>= 1) rsum += __shfl_down(rsum, off);
    if (l == 0) redsum[w] = rsum;

    float* lre = sm + w * 1152;
    float* lim = lre + 576;
    fft512(v, lre, lim, l);
    __syncthreads();   // all waves done with FFT scratch before tile reuse
    if (tid == 0) {
        float s = 0.0f;
#pragma unroll
        for (int i = 0; i < 8; i++) s += redsum[i];
        atomicAdd(meanacc + img, s);
    }

    // unpack packed rows: R1 = (Z + conj(Zflip))/2, R2 = -i(Z - conj(Zflip))/2
    float* tre = sm;            // [16][265]
    float* tim = sm + 4240;
    int lr0 = 2 * w, lr1 = lr0 + 1;
    int sl = (64 - l) & 63;
#pragma unroll
    for (int t = 0; t <= 4; t++) {
        float2 a = v[7 - t];
        float zfx = __shfl(a.x, sl);
        float zfy = __shfl(a.y, sl);
        if (l == 0) { float2 o = v[(8 - t) & 7]; zfx = o.x; zfy = o.y; }
        float2 z = v[t];
        int col = 64 * t + l;
        if (col < NF) {
            tre[lr0 * 265 + col] = 0.5f * (z.x + zfx);
            tim[lr0 * 265 + col] = 0.5f * (z.y - zfy);
            tre[lr1 * 265 + col] = 0.5f * (z.y + zfy);
            tim[lr1 * 265 + col] = 0.5f * (zfx - z.x);
        }
    }
    __syncthreads();

    // coalesced transposed write: 16 consecutive rows per column
    int c0 = tid >> 4, rr = tid & 15;
#pragma unroll
    for (int it = 0; it < 9; it++) {
        int c = it * 32 + c0;
        if (c < NF) {
            float2 val = make_float2(tre[rr * 265 + c], tim[rr * 265 + c]);
            inter[((size_t)img * NF + c) * N + rowbase + rr] = val;
        }
    }
}

// ---------------- column FFT + |F|^2 accumulate (fftshifted, transposed acc) ----
// block = 256 threads = 4 waves = 4 columns; loops over 8 images with prefetch;
// grid (65, 16). Mean correction: v = Z[col] - mn * Hrow[col].
__global__ __launch_bounds__(256) void colfft_kernel(const float2* __restrict__ inter,
                                                     const float2* __restrict__ Hrow,
                                                     const float* __restrict__ meanacc,
                                                     float* __restrict__ accT) {
    __shared__ float sm[4608];
    int tid = threadIdx.x;
    int w = tid >> 6, l = tid & 63;
    int col = blockIdx.x * 4 + w;
    int colc = col < NF ? col : NF - 1;
    int b0 = blockIdx.y * 8;
    float* lre = sm + w * 1152;
    float* lim = lre + 576;
    int rl = __brev((unsigned)l) >> 26;

    int off[8];
#pragma unroll
    for (int e = 0; e < 8; e++)
        off[e] = (int)((__brev((unsigned)e) >> 29) << 6) + rl;

    float2 hv[8];
    const float2* hbase = Hrow + (size_t)colc * N;
#pragma unroll
    for (int e = 0; e < 8; e++) hv[e] = hbase[off[e]];

    float pw[8];
#pragma unroll
    for (int t = 0; t < 8; t++) pw[t] = 0.0f;

    float2 nv[8];
    const float2* base0 = inter + ((size_t)b0 * NF + colc) * N;
#pragma unroll
    for (int e = 0; e < 8; e++) nv[e] = base0[off[e]];

    for (int bi = 0; bi < 8; bi++) {
        float mn = meanacc[b0 + bi] * (1.0f / ((float)N * (float)N));
        float2 v[8];
#pragma unroll
        for (int e = 0; e < 8; e++)
            v[e] = make_float2(nv[e].x - mn * hv[e].x, nv[e].y - mn * hv[e].y);
        if (bi < 7) {
            const float2* nb = inter + ((size_t)(b0 + bi + 1) * NF + colc) * N;
#pragma unroll
            for (int e = 0; e < 8; e++) nv[e] = nb[off[e]];
        }
        fft512(v, lre, lim, l);
#pragma unroll
        for (int t = 0; t < 8; t++)
            pw[t] += v[t].x * v[t].x + v[t].y * v[t].y;
    }

    if (col < NF) {
        int sv = (col + 256) & 511;
#pragma unroll
        for (int t = 0; t < 8; t++) {
            int k = 64 * t + l;
            int su = (k + 256) & 511;
            atomicAdd(&accT[(size_t)sv * N + su], pw[t]);
        }
        if (col >= 1 && col <= 255) {   // Hermitian mirror: P(512-k, 512-col) = P(k, col)
            int sv2 = (768 - col) & 511;
#pragma unroll
            for (int t = 0; t < 8; t++) {
                int k = 64 * t + l;
                int su2 = (768 - k) & 511;
                atomicAdd(&accT[(size_t)sv2 * N + su2], pw[t]);
            }
        }
    }
}

// ---------------- finalize: nps2D + radial bin partial sums ----------------
// Reads accT coalesced; scatters out2d writes (stores don't stall).
__global__ __launch_bounds__(256) void finalize2d_kernel(const float* __restrict__ accT,
                                                         float* __restrict__ out2d,
                                                         float* __restrict__ bins) {
    __shared__ float lsum[NF];
    __shared__ float lcnt[NF];
    int t = threadIdx.x;
    for (int i = t; i < NF; i += 256) { lsum[i] = 0.0f; lcnt[i] = 0.0f; }
    __syncthreads();
    const float scale = (0.1f * 0.1f) / ((float)N * (float)N) / (float)NB;
    int idx = blockIdx.x * 256 + t;
    int stride = gridDim.x * 256;
    for (int q = idx; q < N * N; q += stride) {
        int j = q >> 9, i = q & (N - 1);   // accT[q] = acc value at out2d[i*N+j]
        float v = accT[q] * scale;
        out2d[(size_t)i * N + j] = v;
        float xi = (float)(i - N / 2), yj = (float)(j - N / 2);
        int rad = (int)rintf(sqrtf(xi * xi + yj * yj));
        if (rad < NF) {
            atomicAdd(&lsum[rad], v);
            atomicAdd(&lcnt[rad], 1.0f);
        }
    }
    __syncthreads();
    for (int i = t; i < NF; i += 256) {
        if (lsum[i] != 0.0f || lcnt[i] != 0.0f) {
            atomicAdd(&bins[i], lsum[i]);
            atomicAdd(&bins[NF + 1 + i], lcnt[i]);
        }
    }
}

// ---------------- finalize: nps1D + f1D ----------------
__global__ void finalize1d_kernel(const float* __restrict__ bins, float* __restrict__ out) {
    int t = blockIdx.x * blockDim.x + threadIdx.x;
    if (t < NF) {
        out[t] = bins[t] / bins[NF + 1 + t];                 // nps1D
        out[NF + N * N + t] = (float)t * (5.0f / 256.0f);    // f1D (nyquist = 5)
    }
}

extern "C" void kernel_launch(void* const* d_in, const int* in_sizes, int n_in,
                              void* d_out, int out_size, void* d_ws, size_t ws_size,
                              hipStream_t stream) {
    const float* x = (const float*)d_in[0];
    float* out = (float*)d_out;
    char* ws = (char*)d_ws;

    float* accT    = (float*)ws;                                    // N*N floats (transposed)
    float* meanacc = (float*)(ws + (size_t)N * N * sizeof(float));  // NB floats
    float* bins    = meanacc + NB;                                  // 2*(NF+1) floats
    size_t off_h = (size_t)N * N * sizeof(float) + NB * sizeof(float)
                   + 2 * (NF + 1) * sizeof(float);
    off_h = (off_h + 255) & ~(size_t)255;
    float2* Hrow = (float2*)(ws + off_h);                           // [NF][N] float2 ~ 1.05 MB
    size_t off_inter = off_h + (size_t)NF * N * sizeof(float2);
    off_inter = (off_inter + 255) & ~(size_t)255;
    float2* inter = (float2*)(ws + off_inter);   // [NB][NF][N] float2 = 134.7 MB

    zero_kernel<<<dim3((N * N + 255) / 256), dim3(256), 0, stream>>>(accT, bins, meanacc);
    hannfft_kernel<<<dim3(32), dim3(512), 0, stream>>>(Hrow);
    rowfft_kernel<<<dim3(NB * 32), dim3(512), 0, stream>>>(x, meanacc, inter);
    colfft_kernel<<<dim3(65, 16), dim3(256), 0, stream>>>(inter, Hrow, meanacc, accT);
    finalize2d_kernel<<<dim3(256), dim3(256), 0, stream>>>(accT, out + NF, bins);
    finalize1d_kernel<<<dim3(2), dim3(256), 0, stream>>>(bins, out);
}

// Round 6
// 270.392 us; speedup vs baseline: 2.6797x; 1.0226x over previous
//
#include <hip/hip_runtime.h>
#include <hip/hip_fp16.h>

#define N 512
#define NF 257        // n_freq = N/2 + 1
#define NB 128        // batch
#define PI_F 3.14159265358979323846f
#define C_SQ2 0.70710678118654752440f

__device__ __forceinline__ float2 cmul(float2 a, float2 b) {
    return make_float2(a.x * b.x - a.y * b.y, a.x * b.y + a.y * b.x);
}
__device__ __forceinline__ void bf(float2& a, float2& b) {
    float2 t = b;
    b = make_float2(a.x - t.x, a.y - t.y);
    a = make_float2(a.x + t.x, a.y + t.y);
}
__device__ __forceinline__ void bf_tw(float2& a, float2& b, float2 w) {
    float2 t = cmul(b, w);
    b = make_float2(a.x - t.x, a.y - t.y);
    a = make_float2(a.x + t.x, a.y + t.y);
}
__device__ __forceinline__ void bf_ni(float2& a, float2& b) {   // tw = -i
    float2 t = make_float2(b.y, -b.x);
    b = make_float2(a.x - t.x, a.y - t.y);
    a = make_float2(a.x + t.x, a.y + t.y);
}
__device__ __forceinline__ void lds_fence() {
    asm volatile("s_waitcnt lgkmcnt(0)" ::: "memory");
}

// 512-pt FFT per wave (64 lanes x 8 float2 regs).
// Input: v[e] = x[brev9(8*l + e)] (bit-reversed load done by caller).
// Output: lane l holds X[64*t + l] in v[t] (natural order).
// lre/lim: per-wave LDS scratch, 576 floats each (padded i + (i>>3)).
__device__ __forceinline__ void fft512(float2 v[8], float* lre, float* lim, int l) {
    const float2 w64  = make_float2(C_SQ2, -C_SQ2);    // w^64  = e^{-i pi/4}
    const float2 w192 = make_float2(-C_SQ2, -C_SQ2);   // w^192 = e^{-3i pi/4}
    // ---- phase A: stages 1-3 (strides 1,2,4) in registers ----
    bf(v[0], v[1]); bf(v[2], v[3]); bf(v[4], v[5]); bf(v[6], v[7]);
    bf(v[0], v[2]); bf_ni(v[1], v[3]); bf(v[4], v[6]); bf_ni(v[5], v[7]);
    bf(v[0], v[4]); bf_tw(v[1], v[5], w64); bf_ni(v[2], v[6]); bf_tw(v[3], v[7], w192);
    // ---- transpose A->B: idx = 8l+e  ->  idx = 64g+8t+r ----
#pragma unroll
    for (int e = 0; e < 8; e++) { lre[9 * l + e] = v[e].x; lim[9 * l + e] = v[e].y; }
    lds_fence();
    int g = l >> 3, r = l & 7;
#pragma unroll
    for (int t = 0; t < 8; t++) {
        int p = 72 * g + 9 * t + r;
        v[t].x = lre[p]; v[t].y = lim[p];
    }
    // ---- phase B: stages 4-6 (strides 8,16,32) ----
    float sn, cs;
    __sincosf(-(PI_F / 32.0f) * (float)r, &sn, &cs);
    float2 W1 = make_float2(cs, sn);        // w^(8r)
    float2 W2 = cmul(W1, W1);               // w^(16r)
    float2 W3 = cmul(W2, W2);               // w^(32r)
    float2 W2n = make_float2(W2.y, -W2.x);
    bf_tw(v[0], v[1], W3); bf_tw(v[2], v[3], W3); bf_tw(v[4], v[5], W3); bf_tw(v[6], v[7], W3);
    bf_tw(v[0], v[2], W2); bf_tw(v[1], v[3], W2n); bf_tw(v[4], v[6], W2); bf_tw(v[5], v[7], W2n);
    {
        float2 W1a = cmul(W1, w64);
        float2 W1n = make_float2(W1.y, -W1.x);
        float2 W1c = cmul(W1, w192);
        bf_tw(v[0], v[4], W1); bf_tw(v[1], v[5], W1a); bf_tw(v[2], v[6], W1n); bf_tw(v[3], v[7], W1c);
    }
    // ---- transpose B->C: -> lane c holds idx = 64t + c ----
#pragma unroll
    for (int t = 0; t < 8; t++) {
        int p = 72 * g + 9 * t + r;
        lre[p] = v[t].x; lim[p] = v[t].y;
    }
    lds_fence();
#pragma unroll
    for (int t = 0; t < 8; t++) {
        int p = 72 * t + l + (l >> 3);
        v[t].x = lre[p]; v[t].y = lim[p];
    }
    // ---- phase C: stages 7-9 (strides 64,128,256) ----
    __sincosf(-(PI_F / 256.0f) * (float)l, &sn, &cs);
    float2 Wc = make_float2(cs, sn);        // w^c
    float2 w2 = cmul(Wc, Wc);               // w^(2c)
    float2 w4 = cmul(w2, w2);               // w^(4c)
    float2 w2n = make_float2(w2.y, -w2.x);
    bf_tw(v[0], v[1], w4); bf_tw(v[2], v[3], w4); bf_tw(v[4], v[5], w4); bf_tw(v[6], v[7], w4);
    bf_tw(v[0], v[2], w2); bf_tw(v[1], v[3], w2n); bf_tw(v[4], v[6], w2); bf_tw(v[5], v[7], w2n);
    {
        float2 Wca = cmul(Wc, w64);
        float2 Wcn = make_float2(Wc.y, -Wc.x);
        float2 Wcc = cmul(Wc, w192);
        bf_tw(v[0], v[4], Wc); bf_tw(v[1], v[5], Wca); bf_tw(v[2], v[6], Wcn); bf_tw(v[3], v[7], Wcc);
    }
}

// ---------------- zero accumulators ----------------
__global__ void zero_kernel(float* __restrict__ acc, float* __restrict__ bins,
                            float* __restrict__ meanacc) {
    int i = blockIdx.x * blockDim.x + threadIdx.x;
    if (i < N * N) acc[i] = 0.0f;
    if (i < 2 * (NF + 1)) bins[i] = 0.0f;
    if (i < NB) meanacc[i] = 0.0f;
}

// ---------------- Hann window table (1 MB, L2-resident afterwards) ----------
__global__ __launch_bounds__(256) void hanntab_kernel(float* __restrict__ htab) {
    int i = blockIdx.x * 256 + threadIdx.x;
    int r = i >> 9, c = i & (N - 1);
    const float step = (float)N / (float)(N - 1);
    float a = -0.5f * (float)N + (float)r * step;
    float b = -0.5f * (float)N + (float)c * step;
    float rr = sqrtf(a * a + b * b);
    float h = (rr > 256.0f) ? 0.0f : 0.5f * (1.0f + cosf(rr * (PI_F / 256.0f)));
    htab[i] = h;
}

// ---------------- rowFFT of the Hann window itself (once per launch) ----------
// Hrow layout: [col 0..256][row 0..511] float2 (fp32, small).
__global__ __launch_bounds__(512) void hannfft_kernel(const float* __restrict__ htab,
                                                      float2* __restrict__ Hrow) {
    __shared__ float sm[9216];
    int tid = threadIdx.x;
    int w = tid >> 6, l = tid & 63;
    int rowbase = blockIdx.x << 4;
    int r1 = rowbase + 2 * w, r2 = r1 + 1;
    const float* h1row = htab + (size_t)r1 * N;
    const float* h2row = htab + (size_t)r2 * N;

    float2 v[8];
    int rl = __brev((unsigned)l) >> 26;
#pragma unroll
    for (int e = 0; e < 8; e++) {
        int src = (int)((__brev((unsigned)e) >> 29) << 6) + rl;
        v[e].x = h1row[src];
        v[e].y = h2row[src];
    }

    float* lre = sm + w * 1152;
    float* lim = lre + 576;
    fft512(v, lre, lim, l);
    __syncthreads();

    float* tre = sm;            // [16][265]
    float* tim = sm + 4240;
    int lr0 = 2 * w, lr1 = lr0 + 1;
    int sl = (64 - l) & 63;
#pragma unroll
    for (int t = 0; t <= 4; t++) {
        float2 a = v[7 - t];
        float zfx = __shfl(a.x, sl);
        float zfy = __shfl(a.y, sl);
        if (l == 0) { float2 o = v[(8 - t) & 7]; zfx = o.x; zfy = o.y; }
        float2 z = v[t];
        int col = 64 * t + l;
        if (col < NF) {
            tre[lr0 * 265 + col] = 0.5f * (z.x + zfx);
            tim[lr0 * 265 + col] = 0.5f * (z.y - zfy);
            tre[lr1 * 265 + col] = 0.5f * (z.y + zfy);
            tim[lr1 * 265 + col] = 0.5f * (zfx - z.x);
        }
    }
    __syncthreads();

    int c0 = tid >> 4, rr = tid & 15;
#pragma unroll
    for (int it = 0; it < 9; it++) {
        int c = it * 32 + c0;
        if (c < NF) {
            float2 val = make_float2(tre[rr * 265 + c], tim[rr * 265 + c]);
            Hrow[(size_t)c * N + rowbase + rr] = val;
        }
    }
}

// ---------------- row FFT: 2 real rows packed per wave, Hermitian half stored ----
// block = 512 threads = 8 waves = 16 rows of one image. Mean handled in colfft
// via linearity; accumulates raw row sums into meanacc. inter is fp16 (half2).
__global__ __launch_bounds__(512) void rowfft_kernel(const float* __restrict__ x,
                                                     const float* __restrict__ htab,
                                                     float* __restrict__ meanacc,
                                                     __half2* __restrict__ inter) {
    __shared__ float sm[9216];   // 8 waves * 1152 floats FFT scratch; reused as half2[16][265]
    __shared__ float redsum[8];
    int tid = threadIdx.x;
    int w = tid >> 6, l = tid & 63;
    int img = blockIdx.x >> 5;
    int rowbase = (blockIdx.x & 31) << 4;
    int r1 = rowbase + 2 * w, r2 = r1 + 1;
    const float* x1 = x + ((size_t)img * N + r1) * N;
    const float* x2 = x1 + N;
    const float* h1row = htab + (size_t)r1 * N;
    const float* h2row = htab + (size_t)r2 * N;

    float2 v[8];
    float rsum = 0.0f;
    int rl = __brev((unsigned)l) >> 26;
#pragma unroll
    for (int e = 0; e < 8; e++) {
        int src = (int)((__brev((unsigned)e) >> 29) << 6) + rl;
        float xv1 = x1[src], xv2 = x2[src];
        rsum += xv1 + xv2;
        v[e].x = xv1 * h1row[src];
        v[e].y = xv2 * h2row[src];
    }
#pragma unroll
    for (int off = 32; off > 0; off >>= 1) rsum += __shfl_down(rsum, off);
    if (l == 0) redsum[w] = rsum;

    float* lre = sm + w * 1152;
    float* lim = lre + 576;
    fft512(v, lre, lim, l);
    __syncthreads();   // all waves done with FFT scratch before tile reuse
    if (tid == 0) {
        float s = 0.0f;
#pragma unroll
        for (int i = 0; i < 8; i++) s += redsum[i];
        atomicAdd(meanacc + img, s);
    }

    // unpack packed rows: R1 = (Z + conj(Zflip))/2, R2 = -i(Z - conj(Zflip))/2
    __half2* tile = (__half2*)sm;    // [16][265]
    int lr0 = 2 * w, lr1 = lr0 + 1;
    int sl = (64 - l) & 63;
#pragma unroll
    for (int t = 0; t <= 4; t++) {
        float2 a = v[7 - t];
        float zfx = __shfl(a.x, sl);
        float zfy = __shfl(a.y, sl);
        if (l == 0) { float2 o = v[(8 - t) & 7]; zfx = o.x; zfy = o.y; }
        float2 z = v[t];
        int col = 64 * t + l;
        if (col < NF) {
            tile[lr0 * 265 + col] = __floats2half2_rn(0.5f * (z.x + zfx), 0.5f * (z.y - zfy));
            tile[lr1 * 265 + col] = __floats2half2_rn(0.5f * (z.y + zfy), 0.5f * (zfx - z.x));
        }
    }
    __syncthreads();

    // coalesced transposed write: 16 consecutive rows per column
    int c0 = tid >> 4, rr = tid & 15;
#pragma unroll
    for (int it = 0; it < 9; it++) {
        int c = it * 32 + c0;
        if (c < NF) {
            inter[((size_t)img * NF + c) * N + rowbase + rr] = tile[rr * 265 + c];
        }
    }
}

// ---------------- column FFT + |F|^2 accumulate (fftshifted, transposed acc) ----
// block = 256 threads = 4 waves = 4 columns; loops over 8 images with prefetch;
// grid (65, 16). Mean correction: v = Z[col] - mn * Hrow[col].
__global__ __launch_bounds__(256) void colfft_kernel(const __half2* __restrict__ inter,
                                                     const float2* __restrict__ Hrow,
                                                     const float* __restrict__ meanacc,
                                                     float* __restrict__ accT) {
    __shared__ float sm[4608];
    int tid = threadIdx.x;
    int w = tid >> 6, l = tid & 63;
    int col = blockIdx.x * 4 + w;
    int colc = col < NF ? col : NF - 1;
    int b0 = blockIdx.y * 8;
    float* lre = sm + w * 1152;
    float* lim = lre + 576;
    int rl = __brev((unsigned)l) >> 26;

    int off[8];
#pragma unroll
    for (int e = 0; e < 8; e++)
        off[e] = (int)((__brev((unsigned)e) >> 29) << 6) + rl;

    float2 hv[8];
    const float2* hbase = Hrow + (size_t)colc * N;
#pragma unroll
    for (int e = 0; e < 8; e++) hv[e] = hbase[off[e]];

    float pw[8];
#pragma unroll
    for (int t = 0; t < 8; t++) pw[t] = 0.0f;

    __half2 nv[8];
    const __half2* base0 = inter + ((size_t)b0 * NF + colc) * N;
#pragma unroll
    for (int e = 0; e < 8; e++) nv[e] = base0[off[e]];

    for (int bi = 0; bi < 8; bi++) {
        float mn = meanacc[b0 + bi] * (1.0f / ((float)N * (float)N));
        float2 v[8];
#pragma unroll
        for (int e = 0; e < 8; e++) {
            float2 z = __half22float2(nv[e]);
            v[e] = make_float2(z.x - mn * hv[e].x, z.y - mn * hv[e].y);
        }
        if (bi < 7) {
            const __half2* nb = inter + ((size_t)(b0 + bi + 1) * NF + colc) * N;
#pragma unroll
            for (int e = 0; e < 8; e++) nv[e] = nb[off[e]];
        }
        fft512(v, lre, lim, l);
#pragma unroll
        for (int t = 0; t < 8; t++)
            pw[t] += v[t].x * v[t].x + v[t].y * v[t].y;
    }

    if (col < NF) {
        int sv = (col + 256) & 511;
#pragma unroll
        for (int t = 0; t < 8; t++) {
            int k = 64 * t + l;
            int su = (k + 256) & 511;
            atomicAdd(&accT[(size_t)sv * N + su], pw[t]);
        }
        if (col >= 1 && col <= 255) {   // Hermitian mirror: P(512-k, 512-col) = P(k, col)
            int sv2 = (768 - col) & 511;
#pragma unroll
            for (int t = 0; t < 8; t++) {
                int k = 64 * t + l;
                int su2 = (768 - k) & 511;
                atomicAdd(&accT[(size_t)sv2 * N + su2], pw[t]);
            }
        }
    }
}

// ---------------- finalize: nps2D + radial bin partial sums ----------------
// Reads accT coalesced; scatters out2d writes (stores don't stall).
__global__ __launch_bounds__(256) void finalize2d_kernel(const float* __restrict__ accT,
                                                         float* __restrict__ out2d,
                                                         float* __restrict__ bins) {
    __shared__ float lsum[NF];
    __shared__ float lcnt[NF];
    int t = threadIdx.x;
    for (int i = t; i < NF; i += 256) { lsum[i] = 0.0f; lcnt[i] = 0.0f; }
    __syncthreads();
    const float scale = (0.1f * 0.1f) / ((float)N * (float)N) / (float)NB;
    int idx = blockIdx.x * 256 + t;
    int stride = gridDim.x * 256;
    for (int q = idx; q < N * N; q += stride) {
        int j = q >> 9, i = q & (N - 1);   // accT[q] = acc value at out2d[i*N+j]
        float v = accT[q] * scale;
        out2d[(size_t)i * N + j] = v;
        float xi = (float)(i - N / 2), yj = (float)(j - N / 2);
        int rad = (int)rintf(sqrtf(xi * xi + yj * yj));
        if (rad < NF) {
            atomicAdd(&lsum[rad], v);
            atomicAdd(&lcnt[rad], 1.0f);
        }
    }
    __syncthreads();
    for (int i = t; i < NF; i += 256) {
        if (lsum[i] != 0.0f || lcnt[i] != 0.0f) {
            atomicAdd(&bins[i], lsum[i]);
            atomicAdd(&bins[NF + 1 + i], lcnt[i]);
        }
    }
}

// ---------------- finalize: nps1D + f1D ----------------
__global__ void finalize1d_kernel(const float* __restrict__ bins, float* __restrict__ out) {
    int t = blockIdx.x * blockDim.x + threadIdx.x;
    if (t < NF) {
        out[t] = bins[t] / bins[NF + 1 + t];                 // nps1D
        out[NF + N * N + t] = (float)t * (5.0f / 256.0f);    // f1D (nyquist = 5)
    }
}

extern "C" void kernel_launch(void* const* d_in, const int* in_sizes, int n_in,
                              void* d_out, int out_size, void* d_ws, size_t ws_size,
                              hipStream_t stream) {
    const float* x = (const float*)d_in[0];
    float* out = (float*)d_out;
    char* ws = (char*)d_ws;

    float* accT    = (float*)ws;                                    // N*N floats (transposed)
    float* meanacc = (float*)(ws + (size_t)N * N * sizeof(float));  // NB floats
    float* bins    = meanacc + NB;                                  // 2*(NF+1) floats
    size_t off_h = (size_t)N * N * sizeof(float) + NB * sizeof(float)
                   + 2 * (NF + 1) * sizeof(float);
    off_h = (off_h + 255) & ~(size_t)255;
    float2* Hrow = (float2*)(ws + off_h);                           // [NF][N] float2 ~ 1.05 MB
    size_t off_t = off_h + (size_t)NF * N * sizeof(float2);
    off_t = (off_t + 255) & ~(size_t)255;
    float* htab = (float*)(ws + off_t);                             // [N][N] float = 1 MB
    size_t off_inter = off_t + (size_t)N * N * sizeof(float);
    off_inter = (off_inter + 255) & ~(size_t)255;
    __half2* inter = (__half2*)(ws + off_inter);  // [NB][NF][N] half2 = 67.4 MB

    zero_kernel<<<dim3((N * N + 255) / 256), dim3(256), 0, stream>>>(accT, bins, meanacc);
    hanntab_kernel<<<dim3(N * N / 256), dim3(256), 0, stream>>>(htab);
    hannfft_kernel<<<dim3(32), dim3(512), 0, stream>>>(htab, Hrow);
    rowfft_kernel<<<dim3(NB * 32), dim3(512), 0, stream>>>(x, htab, meanacc, inter);
    colfft_kernel<<<dim3(65, 16), dim3(256), 0, stream>>>(inter, Hrow, meanacc, accT);
    finalize2d_kernel<<<dim3(256), dim3(256), 0, stream>>>(accT, out + NF, bins);
    finalize1d_kernel<<<dim3(2), dim3(256), 0, stream>>>(bins, out);
}

// Round 7
// 259.020 us; speedup vs baseline: 2.7974x; 1.0439x over previous
//
#include <hip/hip_runtime.h>
#include <hip/hip_fp16.h>

#define N 512
#define NF 257        // n_freq = N/2 + 1
#define NB 128        // batch
#define PI_F 3.14159265358979323846f
#define C_SQ2 0.70710678118654752440f

__device__ __forceinline__ float2 cmul(float2 a, float2 b) {
    return make_float2(a.x * b.x - a.y * b.y, a.x * b.y + a.y * b.x);
}
__device__ __forceinline__ void bf(float2& a, float2& b) {
    float2 t = b;
    b = make_float2(a.x - t.x, a.y - t.y);
    a = make_float2(a.x + t.x, a.y + t.y);
}
__device__ __forceinline__ void bf_tw(float2& a, float2& b, float2 w) {
    float2 t = cmul(b, w);
    b = make_float2(a.x - t.x, a.y - t.y);
    a = make_float2(a.x + t.x, a.y + t.y);
}
__device__ __forceinline__ void bf_ni(float2& a, float2& b) {   // tw = -i
    float2 t = make_float2(b.y, -b.x);
    b = make_float2(a.x - t.x, a.y - t.y);
    a = make_float2(a.x + t.x, a.y + t.y);
}
__device__ __forceinline__ void lds_fence() {
    asm volatile("s_waitcnt lgkmcnt(0)" ::: "memory");
}

// 512-pt FFT per wave, float2 AoS LDS scratch (576 float2 per wave, pad p=q+(q>>3)).
// Core: input v[e] = x[brev9(8*l + e)]; output lane l holds X[64*t + l] in v[t].
__device__ __forceinline__ void fft512_core(float2 v[8], float2* st, int l) {
    const float2 w64  = make_float2(C_SQ2, -C_SQ2);    // e^{-i pi/4}
    const float2 w192 = make_float2(-C_SQ2, -C_SQ2);   // e^{-3i pi/4}
    // ---- phase A: stages 1-3 in registers ----
    bf(v[0], v[1]); bf(v[2], v[3]); bf(v[4], v[5]); bf(v[6], v[7]);
    bf(v[0], v[2]); bf_ni(v[1], v[3]); bf(v[4], v[6]); bf_ni(v[5], v[7]);
    bf(v[0], v[4]); bf_tw(v[1], v[5], w64); bf_ni(v[2], v[6]); bf_tw(v[3], v[7], w192);
    // ---- transpose A->B ----
#pragma unroll
    for (int e = 0; e < 8; e++) st[9 * l + e] = v[e];
    lds_fence();
    int g = l >> 3, r = l & 7;
#pragma unroll
    for (int t = 0; t < 8; t++) v[t] = st[72 * g + 9 * t + r];
    // ---- phase B: stages 4-6 ----
    float sn, cs;
    __sincosf(-(PI_F / 32.0f) * (float)r, &sn, &cs);
    float2 W1 = make_float2(cs, sn);        // w^(8r)
    float2 W2 = cmul(W1, W1);
    float2 W3 = cmul(W2, W2);
    float2 W2n = make_float2(W2.y, -W2.x);
    bf_tw(v[0], v[1], W3); bf_tw(v[2], v[3], W3); bf_tw(v[4], v[5], W3); bf_tw(v[6], v[7], W3);
    bf_tw(v[0], v[2], W2); bf_tw(v[1], v[3], W2n); bf_tw(v[4], v[6], W2); bf_tw(v[5], v[7], W2n);
    {
        float2 W1a = cmul(W1, w64);
        float2 W1n = make_float2(W1.y, -W1.x);
        float2 W1c = cmul(W1, w192);
        bf_tw(v[0], v[4], W1); bf_tw(v[1], v[5], W1a); bf_tw(v[2], v[6], W1n); bf_tw(v[3], v[7], W1c);
    }
    // ---- transpose B->C ----
#pragma unroll
    for (int t = 0; t < 8; t++) st[72 * g + 9 * t + r] = v[t];
    lds_fence();
#pragma unroll
    for (int t = 0; t < 8; t++) v[t] = st[72 * t + l + (l >> 3)];
    // ---- phase C: stages 7-9 ----
    __sincosf(-(PI_F / 256.0f) * (float)l, &sn, &cs);
    float2 Wc = make_float2(cs, sn);
    float2 w2 = cmul(Wc, Wc);
    float2 w4 = cmul(w2, w2);
    float2 w2n = make_float2(w2.y, -w2.x);
    bf_tw(v[0], v[1], w4); bf_tw(v[2], v[3], w4); bf_tw(v[4], v[5], w4); bf_tw(v[6], v[7], w4);
    bf_tw(v[0], v[2], w2); bf_tw(v[1], v[3], w2n); bf_tw(v[4], v[6], w2); bf_tw(v[5], v[7], w2n);
    {
        float2 Wca = cmul(Wc, w64);
        float2 Wcn = make_float2(Wc.y, -Wc.x);
        float2 Wcc = cmul(Wc, w192);
        bf_tw(v[0], v[4], Wc); bf_tw(v[1], v[5], Wca); bf_tw(v[2], v[6], Wcn); bf_tw(v[3], v[7], Wcc);
    }
}

// Natural-order entry: v[e] = x[8*l + e]; does LDS bit-reversal pre-permute, then core.
__device__ __forceinline__ void fft512_nat(float2 v[8], float2* st, int l) {
#pragma unroll
    for (int e = 0; e < 8; e++) st[9 * l + e] = v[e];   // natural idx 8l+e, padded
    lds_fence();
    int rl = __brev((unsigned)l) >> 26;
    int rp = rl + (rl >> 3);
    const int bre[8] = {0, 4, 2, 6, 1, 5, 3, 7};        // brev3
#pragma unroll
    for (int e = 0; e < 8; e++) v[e] = st[72 * bre[e] + rp];
    fft512_core(v, st, l);
}

// ---------------- zero accumulators ----------------
__global__ void zero_kernel(float* __restrict__ accH, float* __restrict__ bins,
                            float* __restrict__ meanacc) {
    int i = blockIdx.x * blockDim.x + threadIdx.x;
    if (i < NF * N) accH[i] = 0.0f;
    if (i < 2 * (NF + 1)) bins[i] = 0.0f;
    if (i < NB) meanacc[i] = 0.0f;
}

// ---------------- Hann window table (1 MB, L2-resident afterwards) ----------
__global__ __launch_bounds__(256) void hanntab_kernel(float* __restrict__ htab) {
    int i = blockIdx.x * 256 + threadIdx.x;
    int r = i >> 9, c = i & (N - 1);
    const float step = (float)N / (float)(N - 1);
    float a = -0.5f * (float)N + (float)r * step;
    float b = -0.5f * (float)N + (float)c * step;
    float rr = sqrtf(a * a + b * b);
    float h = (rr > 256.0f) ? 0.0f : 0.5f * (1.0f + cosf(rr * (PI_F / 256.0f)));
    htab[i] = h;
}

// ---------------- rowFFT of the Hann window itself (once per launch) ----------
// Hrow layout: [col 0..256][row 0..511] float2 (fp32).
__global__ __launch_bounds__(512) void hannfft_kernel(const float* __restrict__ htab,
                                                      float2* __restrict__ Hrow) {
    __shared__ float sm[9216];
    int tid = threadIdx.x;
    int w = tid >> 6, l = tid & 63;
    int rowbase = blockIdx.x << 4;
    int r1 = rowbase + 2 * w, r2 = r1 + 1;
    const float4* h1 = (const float4*)(htab + (size_t)r1 * N) + 2 * l;
    const float4* h2 = (const float4*)(htab + (size_t)r2 * N) + 2 * l;
    float4 ha = h1[0], hb = h1[1], hc = h2[0], hd = h2[1];

    float2 v[8];
    v[0] = make_float2(ha.x, hc.x); v[1] = make_float2(ha.y, hc.y);
    v[2] = make_float2(ha.z, hc.z); v[3] = make_float2(ha.w, hc.w);
    v[4] = make_float2(hb.x, hd.x); v[5] = make_float2(hb.y, hd.y);
    v[6] = make_float2(hb.z, hd.z); v[7] = make_float2(hb.w, hd.w);

    float2* st = (float2*)sm + w * 576;
    fft512_nat(v, st, l);
    __syncthreads();

    float* tre = sm;            // [16][265]
    float* tim = sm + 4240;
    int lr0 = 2 * w, lr1 = lr0 + 1;
    int sl = (64 - l) & 63;
#pragma unroll
    for (int t = 0; t <= 4; t++) {
        float2 a = v[7 - t];
        float zfx = __shfl(a.x, sl);
        float zfy = __shfl(a.y, sl);
        if (l == 0) { float2 o = v[(8 - t) & 7]; zfx = o.x; zfy = o.y; }
        float2 z = v[t];
        int col = 64 * t + l;
        if (col < NF) {
            tre[lr0 * 265 + col] = 0.5f * (z.x + zfx);
            tim[lr0 * 265 + col] = 0.5f * (z.y - zfy);
            tre[lr1 * 265 + col] = 0.5f * (z.y + zfy);
            tim[lr1 * 265 + col] = 0.5f * (zfx - z.x);
        }
    }
    __syncthreads();

    int c0 = tid >> 4, rr = tid & 15;
#pragma unroll
    for (int it = 0; it < 9; it++) {
        int c = it * 32 + c0;
        if (c < NF) {
            float2 val = make_float2(tre[rr * 265 + c], tim[rr * 265 + c]);
            Hrow[(size_t)c * N + rowbase + rr] = val;
        }
    }
}

// ---------------- row FFT: 2 real rows packed per wave, Hermitian half stored ----
// Natural-order dwordx4 loads; bit-reversal via LDS pre-permute. inter is fp16.
__global__ __launch_bounds__(512) void rowfft_kernel(const float* __restrict__ x,
                                                     const float* __restrict__ htab,
                                                     float* __restrict__ meanacc,
                                                     __half2* __restrict__ inter) {
    __shared__ float sm[9216];
    __shared__ float redsum[8];
    int tid = threadIdx.x;
    int w = tid >> 6, l = tid & 63;
    int img = blockIdx.x >> 5;
    int rowbase = (blockIdx.x & 31) << 4;
    int r1 = rowbase + 2 * w, r2 = r1 + 1;
    const float4* x1 = (const float4*)(x + ((size_t)img * N + r1) * N) + 2 * l;
    const float4* x2 = (const float4*)(x + ((size_t)img * N + r2) * N) + 2 * l;
    const float4* h1 = (const float4*)(htab + (size_t)r1 * N) + 2 * l;
    const float4* h2 = (const float4*)(htab + (size_t)r2 * N) + 2 * l;

    float4 xa = x1[0], xb = x1[1], xc = x2[0], xd = x2[1];
    float4 ha = h1[0], hb = h1[1], hc = h2[0], hd = h2[1];

    float rsum = ((xa.x + xa.y) + (xa.z + xa.w)) + ((xb.x + xb.y) + (xb.z + xb.w))
               + ((xc.x + xc.y) + (xc.z + xc.w)) + ((xd.x + xd.y) + (xd.z + xd.w));

    float2 v[8];
    v[0] = make_float2(xa.x * ha.x, xc.x * hc.x);
    v[1] = make_float2(xa.y * ha.y, xc.y * hc.y);
    v[2] = make_float2(xa.z * ha.z, xc.z * hc.z);
    v[3] = make_float2(xa.w * ha.w, xc.w * hc.w);
    v[4] = make_float2(xb.x * hb.x, xd.x * hd.x);
    v[5] = make_float2(xb.y * hb.y, xd.y * hd.y);
    v[6] = make_float2(xb.z * hb.z, xd.z * hd.z);
    v[7] = make_float2(xb.w * hb.w, xd.w * hd.w);

#pragma unroll
    for (int off = 32; off > 0; off >>= 1) rsum += __shfl_down(rsum, off);
    if (l == 0) redsum[w] = rsum;

    float2* st = (float2*)sm + w * 576;
    fft512_nat(v, st, l);
    __syncthreads();   // all waves done with FFT scratch before tile reuse
    if (tid == 0) {
        float s = 0.0f;
#pragma unroll
        for (int i = 0; i < 8; i++) s += redsum[i];
        atomicAdd(meanacc + img, s);
    }

    // unpack packed rows: R1 = (Z + conj(Zflip))/2, R2 = -i(Z - conj(Zflip))/2
    __half2* tile = (__half2*)sm;    // [16][265]
    int lr0 = 2 * w, lr1 = lr0 + 1;
    int sl = (64 - l) & 63;
#pragma unroll
    for (int t = 0; t <= 4; t++) {
        float2 a = v[7 - t];
        float zfx = __shfl(a.x, sl);
        float zfy = __shfl(a.y, sl);
        if (l == 0) { float2 o = v[(8 - t) & 7]; zfx = o.x; zfy = o.y; }
        float2 z = v[t];
        int col = 64 * t + l;
        if (col < NF) {
            tile[lr0 * 265 + col] = __floats2half2_rn(0.5f * (z.x + zfx), 0.5f * (z.y - zfy));
            tile[lr1 * 265 + col] = __floats2half2_rn(0.5f * (z.y + zfy), 0.5f * (zfx - z.x));
        }
    }
    __syncthreads();

    // coalesced transposed write: 16 consecutive rows per column
    int c0 = tid >> 4, rr = tid & 15;
#pragma unroll
    for (int it = 0; it < 9; it++) {
        int c = it * 32 + c0;
        if (c < NF) {
            inter[((size_t)img * NF + c) * N + rowbase + rr] = tile[rr * 265 + c];
        }
    }
}

// ---------------- column FFT + |F|^2 half-plane accumulate ----------------
// block = 256 threads = 4 waves = 4 columns; 8 images per group with prefetch;
// natural-order 16B loads; accH[col][k] (no shift/mirror here).
__global__ __launch_bounds__(256) void colfft_kernel(const __half2* __restrict__ inter,
                                                     const float2* __restrict__ Hrow,
                                                     const float* __restrict__ meanacc,
                                                     float* __restrict__ accH) {
    __shared__ float sm[4608];
    int tid = threadIdx.x;
    int w = tid >> 6, l = tid & 63;
    int col = blockIdx.x * 4 + w;
    int colc = col < NF ? col : NF - 1;
    int b0 = blockIdx.y * 8;
    float2* st = (float2*)sm + w * 576;

    union F4F2 { float4 f[4]; float2 c[8]; } hu;
    const float4* hp = (const float4*)(Hrow + (size_t)colc * N + 8 * l);
#pragma unroll
    for (int q = 0; q < 4; q++) hu.f[q] = hp[q];

    float pw[8];
#pragma unroll
    for (int t = 0; t < 8; t++) pw[t] = 0.0f;

    union F4H { float4 f; __half2 h[4]; };
    F4H na, nb;
    const float4* p0 = (const float4*)(inter + ((size_t)b0 * NF + colc) * N + 8 * l);
    na.f = p0[0]; nb.f = p0[1];

    for (int bi = 0; bi < 8; bi++) {
        float mn = meanacc[b0 + bi] * (1.0f / ((float)N * (float)N));
        float2 v[8];
#pragma unroll
        for (int e = 0; e < 4; e++) {
            float2 z = __half22float2(na.h[e]);
            v[e] = make_float2(z.x - mn * hu.c[e].x, z.y - mn * hu.c[e].y);
        }
#pragma unroll
        for (int e = 0; e < 4; e++) {
            float2 z = __half22float2(nb.h[e]);
            v[4 + e] = make_float2(z.x - mn * hu.c[4 + e].x, z.y - mn * hu.c[4 + e].y);
        }
        if (bi < 7) {
            const float4* np = (const float4*)(inter + ((size_t)(b0 + bi + 1) * NF + colc) * N + 8 * l);
            na.f = np[0]; nb.f = np[1];
        }
        fft512_nat(v, st, l);
#pragma unroll
        for (int t = 0; t < 8; t++)
            pw[t] += v[t].x * v[t].x + v[t].y * v[t].y;
    }

    if (col < NF) {
#pragma unroll
        for (int t = 0; t < 8; t++)
            atomicAdd(&accH[(size_t)col * N + 64 * t + l], pw[t]);
    }
}

// ---------------- finalize: nps2D (with Hermitian mirror) + radial bins ------
// Iterates accH coalesced; scatters out2d stores (latency-tolerant).
__global__ __launch_bounds__(256) void finalize2d_kernel(const float* __restrict__ accH,
                                                         float* __restrict__ out2d,
                                                         float* __restrict__ bins) {
    __shared__ float lsum[NF];
    __shared__ float lcnt[NF];
    int t = threadIdx.x;
    for (int i = t; i < NF; i += 256) { lsum[i] = 0.0f; lcnt[i] = 0.0f; }
    __syncthreads();
    const float scale = (0.1f * 0.1f) / ((float)N * (float)N) / (float)NB;
    int idx = blockIdx.x * 256 + t;
    int stride = gridDim.x * 256;
    for (int q = idx; q < NF * N; q += stride) {
        int col = q >> 9, k = q & (N - 1);
        float v = accH[q] * scale;
        // direct pixel
        int i1 = (k + 256) & 511, j1 = (col + 256) & 511;
        out2d[(size_t)i1 * N + j1] = v;
        float xi = (float)(i1 - 256), yj = (float)(j1 - 256);
        int rad = (int)rintf(sqrtf(xi * xi + yj * yj));
        if (rad < NF) { atomicAdd(&lsum[rad], v); atomicAdd(&lcnt[rad], 1.0f); }
        // Hermitian mirror pixel
        if (col >= 1 && col <= 255) {
            int i2 = (256 - k) & 511, j2 = (256 - col) & 511;
            out2d[(size_t)i2 * N + j2] = v;
            float xi2 = (float)(i2 - 256), yj2 = (float)(j2 - 256);
            int rad2 = (int)rintf(sqrtf(xi2 * xi2 + yj2 * yj2));
            if (rad2 < NF) { atomicAdd(&lsum[rad2], v); atomicAdd(&lcnt[rad2], 1.0f); }
        }
    }
    __syncthreads();
    for (int i = t; i < NF; i += 256) {
        if (lsum[i] != 0.0f || lcnt[i] != 0.0f) {
            atomicAdd(&bins[i], lsum[i]);
            atomicAdd(&bins[NF + 1 + i], lcnt[i]);
        }
    }
}

// ---------------- finalize: nps1D + f1D ----------------
__global__ void finalize1d_kernel(const float* __restrict__ bins, float* __restrict__ out) {
    int t = blockIdx.x * blockDim.x + threadIdx.x;
    if (t < NF) {
        out[t] = bins[t] / bins[NF + 1 + t];                 // nps1D
        out[NF + N * N + t] = (float)t * (5.0f / 256.0f);    // f1D (nyquist = 5)
    }
}

extern "C" void kernel_launch(void* const* d_in, const int* in_sizes, int n_in,
                              void* d_out, int out_size, void* d_ws, size_t ws_size,
                              hipStream_t stream) {
    const float* x = (const float*)d_in[0];
    float* out = (float*)d_out;
    char* ws = (char*)d_ws;

    float* accH    = (float*)ws;                                     // NF*N floats
    float* meanacc = (float*)(ws + (size_t)NF * N * sizeof(float));  // NB floats
    float* bins    = meanacc + NB;                                   // 2*(NF+1) floats
    size_t off_h = (size_t)NF * N * sizeof(float) + NB * sizeof(float)
                   + 2 * (NF + 1) * sizeof(float);
    off_h = (off_h + 255) & ~(size_t)255;
    float2* Hrow = (float2*)(ws + off_h);                            // [NF][N] float2 ~ 1.05 MB
    size_t off_t = off_h + (size_t)NF * N * sizeof(float2);
    off_t = (off_t + 255) & ~(size_t)255;
    float* htab = (float*)(ws + off_t);                              // [N][N] float = 1 MB
    size_t off_inter = off_t + (size_t)N * N * sizeof(float);
    off_inter = (off_inter + 255) & ~(size_t)255;
    __half2* inter = (__half2*)(ws + off_inter);   // [NB][NF][N] half2 = 67.4 MB

    zero_kernel<<<dim3((NF * N + 255) / 256), dim3(256), 0, stream>>>(accH, bins, meanacc);
    hanntab_kernel<<<dim3(N * N / 256), dim3(256), 0, stream>>>(htab);
    hannfft_kernel<<<dim3(32), dim3(512), 0, stream>>>(htab, Hrow);
    rowfft_kernel<<<dim3(NB * 32), dim3(512), 0, stream>>>(x, htab, meanacc, inter);
    colfft_kernel<<<dim3(65, 16), dim3(256), 0, stream>>>(inter, Hrow, meanacc, accH);
    finalize2d_kernel<<<dim3(256), dim3(256), 0, stream>>>(accH, out + NF, bins);
    finalize1d_kernel<<<dim3(2), dim3(256), 0, stream>>>(bins, out);
}